// Round 11
// baseline (442.806 us; speedup 1.0000x reference)
//
#include <hip/hip_runtime.h>
#include <hip/hip_cooperative_groups.h>

namespace cg = cooperative_groups;

// GCN: 3-layer GraphConv (norm='both') + mean over nodes.
// Round 11: dispatch-graph collapse. One cooperative build kernel (hist ->
// reduceN -> tq -> scanC(+inline scanB) -> scatter, + cvt/wprep tail),
// unchanged agg/gemm kernels, one cooperative epilogue (colsum -> final).
// 14 dispatches -> 6. All inner algorithms identical to round 10.
#define N_NODES 50000
#define N_EDGES 800000
#define F 128
#define SCAN_NB 49      // ceil(50000/1024)
#define CH 64           // edge chunks
#define EPC (N_EDGES / CH)   // 12500 edges per chunk
#define HALF 25000      // node half-range (packed 16-bit hist)
#define QTR 12500       // node quarter-range (cursors / float bins)
#define BSTRIDE 17      // uint4 per LDS row (odd -> conflict-free ds_read_b128)
#define AGG_NB (N_NODES / 4)   // 12500 agg blocks (4 waves, 1 row/wave)
#define RED_NB 256      // column-partial blocks

typedef __bf16 bf16x8 __attribute__((ext_vector_type(8)));
typedef float  f32x4  __attribute__((ext_vector_type(4)));
typedef float  f32x2  __attribute__((ext_vector_type(2)));

__device__ inline unsigned short f2bf(float f) {  // RNE fp32 -> bf16 bits
    unsigned u = __float_as_uint(f);
    u += 0x7FFF + ((u >> 16) & 1);
    return (unsigned short)(u >> 16);
}
__device__ inline unsigned packbf2(float a, float b) {
    return (unsigned)f2bf(a) | ((unsigned)f2bf(b) << 16);
}

// ---- fp8 e4m3 (OCP on gfx950) helpers ----
__device__ inline void fp8x8_to_f32(uint2 u, float* f) {
    f32x2 v0 = __builtin_amdgcn_cvt_pk_f32_fp8(u.x, false);
    f32x2 v1 = __builtin_amdgcn_cvt_pk_f32_fp8(u.x, true);
    f32x2 v2 = __builtin_amdgcn_cvt_pk_f32_fp8(u.y, false);
    f32x2 v3 = __builtin_amdgcn_cvt_pk_f32_fp8(u.y, true);
    f[0] = v0.x; f[1] = v0.y; f[2] = v1.x; f[3] = v1.y;
    f[4] = v2.x; f[5] = v2.y; f[6] = v3.x; f[7] = v3.y;
}
__device__ inline unsigned f32x4_to_fp8(float a, float b, float c, float d) {
    unsigned r = __builtin_amdgcn_cvt_pk_fp8_f32(a, b, 0, false);
    r = __builtin_amdgcn_cvt_pk_fp8_f32(c, d, r, true);
    return r;
}

// ============ cooperative build kernel: 256 blocks x 1024 threads ============
// P0 hist | P1 reduceN(+bsums) | P2 tq | P3 scanC(+inline scanB,+colpref,+qt)
// | P4 scatter + cvt/wprep tail. 50 KB LDS union.
__global__ __launch_bounds__(1024) void build_kernel(
        const int* __restrict__ src, const int* __restrict__ dst,
        unsigned short* __restrict__ Hs16, unsigned short* __restrict__ Hd16,
        float* __restrict__ onorm, float* __restrict__ inorm,
        int* __restrict__ degd, int* __restrict__ bsums,
        int* __restrict__ rowst, int* __restrict__ P,
        float* __restrict__ Tq, float* __restrict__ qt,
        int* __restrict__ esrc,
        const float* __restrict__ feat, uint2* __restrict__ xq,
        const float* __restrict__ W1, const float* __restrict__ W2,
        unsigned short* __restrict__ Wt_hi, unsigned short* __restrict__ Wt_lo) {
    cg::grid_group grid = cg::this_grid();
    __shared__ unsigned sh[QTR];   // 50 KB union: hist / float bins / cursors / wsum
    int bx = blockIdx.x, tid = threadIdx.x;

    // ---- P0: chunked histograms, block = (chunk, type, half) ----
    {
        int c = bx >> 2, ty = bx & 1, h = (bx >> 1) & 1;
        const int* ids = ty ? dst : src;
        unsigned short* H = ty ? Hd16 : Hs16;
        int base = h * HALF;
        for (int j = tid; j < HALF / 2; j += 1024) sh[j] = 0;
        __syncthreads();
        int e0 = c * EPC;
        for (int e = e0 + tid; e < e0 + EPC; e += 1024) {
            int id = ids[e] - base;
            if ((unsigned)id < (unsigned)HALF)
                atomicAdd(&sh[id >> 1], 1u << ((id & 1) * 16));
        }
        __syncthreads();
        for (int j = tid; j < HALF / 2; j += 1024)
            *(unsigned*)&H[(size_t)c * N_NODES + base + 2 * j] = sh[j];
    }
    grid.sync();

    // ---- P1: reduce partial hists -> norms, degd; block sums (blocks < 49) ----
    if (bx < SCAN_NB) {
        int* wsum = (int*)sh;
        int i = bx * 1024 + tid;
        int dd = 0;
        if (i < N_NODES) {
            int ds = 0;
            for (int c = 0; c < CH; c++) {
                ds += Hs16[(size_t)c * N_NODES + i];
                dd += Hd16[(size_t)c * N_NODES + i];
            }
            onorm[i] = rsqrtf(fmaxf((float)ds, 1.0f));
            inorm[i] = rsqrtf(fmaxf((float)dd, 1.0f));
            degd[i] = dd;
        }
        int v = dd;
#pragma unroll
        for (int off = 32; off; off >>= 1) v += __shfl_down(v, off);
        if ((tid & 63) == 0) wsum[tid >> 6] = v;
        __syncthreads();
        if (tid == 0) {
            int s = 0;
#pragma unroll
            for (int k = 0; k < 16; k++) s += wsum[k];
            bsums[bx] = s;
        }
    }
    grid.sync();

    // ---- P2: t[s] partials via LDS float bins, block = (chunk, quarter) ----
    {
        float* a = (float*)sh;
        int c = bx >> 2, q = bx & 3;
        int base = q * QTR;
        for (int j = tid; j < QTR; j += 1024) a[j] = 0.0f;
        __syncthreads();
        int e0 = c * EPC;
        for (int e = e0 + tid; e < e0 + EPC; e += 1024) {
            int s = src[e] - base;
            if ((unsigned)s < (unsigned)QTR)
                atomicAdd(&a[s], inorm[dst[e]]);   // LDS float atomic
        }
        __syncthreads();
        for (int j = tid; j < QTR; j += 1024)
            Tq[(size_t)c * N_NODES + base + j] = a[j];
    }
    grid.sync();

    // ---- P3: scanC + inline scanB + colpref + qt (blocks < 49) ----
    if (bx < SCAN_NB) {
        int* wsum = (int*)sh;
        int lane = tid & 63, w = tid >> 6;
        int i = bx * 1024 + tid;
        int v = (i < N_NODES) ? degd[i] : 0;
        int incl = v;
#pragma unroll
        for (int off = 1; off < 64; off <<= 1) {
            int u = __shfl_up(incl, off);
            if (lane >= off) incl += u;
        }
        if (lane == 63) wsum[w] = incl;
        __syncthreads();
        if (tid == 0) {
            int boff = 0;                       // inline scanB
            for (int k = 0; k < bx; k++) boff += bsums[k];
            int s = boff;
#pragma unroll
            for (int k = 0; k < 16; k++) { int x = wsum[k]; wsum[k] = s; s += x; }
        }
        __syncthreads();
        incl += wsum[w];
        if (i < N_NODES) {
            int s = incl - v;              // exclusive prefix
            rowst[i] = s;
            if (i == N_NODES - 1) rowst[N_NODES] = incl;
            float tsum = 0.0f;
            for (int c = 0; c < CH; c++) {
                size_t o = (size_t)c * N_NODES + i;
                P[o] = s; s += Hd16[o];
                tsum += Tq[o];
            }
            qt[i] = tsum;
        }
    }
    grid.sync();

    // ---- P4: atomic-free scatter, block = (chunk, quarter) ----
    {
        int* cur = (int*)sh;
        int c = bx >> 2, q = bx & 3;
        int base = q * QTR;
        for (int j = tid; j < QTR; j += 1024)
            cur[j] = P[(size_t)c * N_NODES + base + j];
        __syncthreads();
        int e0 = c * EPC;
        for (int e = e0 + tid; e < e0 + EPC; e += 1024) {
            int d = dst[e] - base;
            if ((unsigned)d < (unsigned)QTR) {
                int pos = atomicAdd(&cur[d], 1);   // LDS atomic only
                esrc[pos] = src[e];
            }
        }
    }

    // ---- tail (no sync needed; consumed only by later kernels) ----
    int T = gridDim.x * 1024;
    int id0 = bx * 1024 + tid;
    // cvt: feat * onorm[row] -> fp8 xq
    for (int i = id0; i < N_NODES * F / 8; i += T) {
        float wgt = onorm[i >> 4];
        const float4* xv = (const float4*)feat;
        float4 v0 = xv[i * 2], v1 = xv[i * 2 + 1];
        uint2 o;
        o.x = f32x4_to_fp8(v0.x * wgt, v0.y * wgt, v0.z * wgt, v0.w * wgt);
        o.y = f32x4_to_fp8(v1.x * wgt, v1.y * wgt, v1.z * wgt, v1.w * wgt);
        xq[i] = o;
    }
    // wprep: W1,W2 -> n-major bf16 hi+lo split
    for (int i = id0; i < 2 * F * F; i += T) {
        int wi = i >> 14, rem = i & 16383;
        int n = rem >> 7, k = rem & 127;
        const float* W = wi ? W2 : W1;
        float v = W[k * F + n];
        unsigned short hi = f2bf(v);
        float r = v - __uint_as_float((unsigned)hi << 16);
        size_t o = (size_t)wi * F * F + (size_t)n * F + k;
        Wt_hi[o] = hi;
        Wt_lo[o] = f2bf(r);
    }
}

// ---- aggregation: 4 waves/block, 1 dst row/wave; 16 lanes/edge fp8 uint2 ----
__global__ __launch_bounds__(256) void agg_csr_kernel(const uint2* __restrict__ xq,
                                                      uint4* __restrict__ mb,
                                                      const int* __restrict__ rowst,
                                                      const int* __restrict__ esrc,
                                                      const float* __restrict__ inorm) {
    int w = threadIdx.x >> 6;
    int lane = threadIdx.x & 63;
    int g = lane >> 4, t = lane & 15;
    int row = blockIdx.x * 4 + w;
    int beg = __builtin_amdgcn_readfirstlane(rowst[row]);
    int end = __builtin_amdgcn_readfirstlane(rowst[row + 1]);
    float acc[8];
#pragma unroll
    for (int k = 0; k < 8; k++) acc[k] = 0.0f;

    for (int e = beg; e < end; e += 16) {   // clamped, 4 gathers in flight
        int ea = min(e + g,      end - 1);
        int eb = min(e + 4 + g,  end - 1);
        int ec = min(e + 8 + g,  end - 1);
        int ed = min(e + 12 + g, end - 1);
        int sa = esrc[ea], sb = esrc[eb], sc = esrc[ec], sd = esrc[ed];
        uint2 ua = xq[(size_t)sa * 16 + t];
        uint2 ub = xq[(size_t)sb * 16 + t];
        uint2 uc = xq[(size_t)sc * 16 + t];
        uint2 ud = xq[(size_t)sd * 16 + t];
        float wa = (e + g      < end) ? 1.0f : 0.0f;
        float wb = (e + 4 + g  < end) ? 1.0f : 0.0f;
        float wc = (e + 8 + g  < end) ? 1.0f : 0.0f;
        float wd = (e + 12 + g < end) ? 1.0f : 0.0f;
        float fa[8], fb[8], fc[8], fd[8];
        fp8x8_to_f32(ua, fa); fp8x8_to_f32(ub, fb);
        fp8x8_to_f32(uc, fc); fp8x8_to_f32(ud, fd);
#pragma unroll
        for (int k = 0; k < 8; k++)
            acc[k] += fa[k] * wa + fb[k] * wb + fc[k] * wc + fd[k] * wd;
    }
#pragma unroll
    for (int k = 0; k < 8; k++) {
        acc[k] += __shfl_xor(acc[k], 16, 64);
        acc[k] += __shfl_xor(acc[k], 32, 64);
    }
    if (g == 0) {
        float inw = inorm[row];
        uint4 o;
        o.x = packbf2(acc[0] * inw, acc[1] * inw);
        o.y = packbf2(acc[2] * inw, acc[3] * inw);
        o.z = packbf2(acc[4] * inw, acc[5] * inw);
        o.w = packbf2(acc[6] * inw, acc[7] * inw);
        mb[(size_t)row * 16 + t] = o;
    }
}

// ---- MFMA GEMM, LDS-staged B: Y8 = fp8(onorm[row] * relu(A@(Whi+Wlo)+b)) ----
__global__ __launch_bounds__(256) void mfma_gemm_kernel(const unsigned short* __restrict__ A,
                                                        const unsigned short* __restrict__ Wt_hi,
                                                        const unsigned short* __restrict__ Wt_lo,
                                                        const float* __restrict__ bias,
                                                        const float* __restrict__ onorm,
                                                        unsigned char* __restrict__ Y8) {
    __shared__ uint4 sB[F * BSTRIDE];   // 34816 B
    int tid = threadIdx.x;
    int w = tid >> 6;
    int lane = tid & 63;
    int quad = lane >> 4, r16 = lane & 15;
    int row0 = blockIdx.x * 64 + w * 16;

    const uint4* Arow = (const uint4*)(A + (size_t)(row0 + r16) * F);
    uint4 a[4];
#pragma unroll
    for (int kk = 0; kk < 4; kk++) a[kk] = Arow[kk * 4 + quad];

    f32x4 acc[8];
#pragma unroll
    for (int t = 0; t < 8; t++) acc[t] = (f32x4){0.f, 0.f, 0.f, 0.f};

    const uint4* G[2] = {(const uint4*)Wt_hi, (const uint4*)Wt_lo};
#pragma unroll
    for (int ph = 0; ph < 2; ph++) {
        if (ph) __syncthreads();
        for (int j = tid; j < F * 16; j += 256)
            sB[(j >> 4) * BSTRIDE + (j & 15)] = G[ph][j];
        __syncthreads();
#pragma unroll
        for (int kk = 0; kk < 4; kk++) {
            bf16x8 av = __builtin_bit_cast(bf16x8, a[kk]);
#pragma unroll
            for (int t = 0; t < 8; t++) {
                bf16x8 bv = __builtin_bit_cast(bf16x8,
                    sB[(t * 16 + r16) * BSTRIDE + kk * 4 + quad]);
                acc[t] = __builtin_amdgcn_mfma_f32_16x16x32_bf16(av, bv, acc[t], 0, 0, 0);
            }
        }
    }

    float onw[4];
#pragma unroll
    for (int reg = 0; reg < 4; reg++) {
        int row = row0 + quad * 4 + reg;
        onw[reg] = (row < N_NODES) ? onorm[row] : 0.0f;
    }
#pragma unroll
    for (int t = 0; t < 8; t++) {
        int col = t * 16 + r16;
        float bb = bias[col];
#pragma unroll
        for (int reg = 0; reg < 4; reg++) {
            int row = row0 + quad * 4 + reg;
            if (row < N_NODES) {
                float v = fmaxf(acc[t][reg] + bb, 0.0f) * onw[reg];
                unsigned p = __builtin_amdgcn_cvt_pk_fp8_f32(v, v, 0, false);
                Y8[(size_t)row * F + col] = (unsigned char)(p & 0xFF);
            }
        }
    }
}

// ============ cooperative epilogue: colsum (256 blocks) -> final ============
__global__ __launch_bounds__(256) void epi_kernel(const unsigned short* __restrict__ x8,
                                                  const float* __restrict__ qt,
                                                  float* __restrict__ part2,
                                                  const float* __restrict__ W3,
                                                  const float* __restrict__ b3,
                                                  float* __restrict__ out) {
    cg::grid_group grid = cg::this_grid();
    __shared__ float sP[4][F];   // 2 KB
    __shared__ float sc2[2][F];
    __shared__ float cvec[F];
    int tid = threadIdx.x;
    int w = tid >> 6, lane = tid & 63;

    // colsum: part2[b][j] = sum_rows qt[r] * fp8dec(x8[r][j])
    float a0 = 0.0f, a1 = 0.0f;
    for (int r = blockIdx.x * 4 + w; r < N_NODES; r += RED_NB * 4) {
        float q = qt[r];
        unsigned us = x8[(size_t)r * 64 + lane];   // 2 fp8 bytes
        f32x2 v = __builtin_amdgcn_cvt_pk_f32_fp8(us, false);
        a0 += v.x * q; a1 += v.y * q;
    }
    sP[w][lane * 2] = a0; sP[w][lane * 2 + 1] = a1;
    __syncthreads();
    if (tid < F)
        part2[(size_t)blockIdx.x * F + tid] =
            sP[0][tid] + sP[1][tid] + sP[2][tid] + sP[3][tid];
    grid.sync();

    // final on block 0: c = (1/N) sum_b part2[b], out = c @ W3 + b3
    if (blockIdx.x == 0) {
        int sl = tid >> 7, col = tid & 127;
        float acc = 0.0f;
        for (int b = sl; b < RED_NB; b += 2) acc += part2[(size_t)b * F + col];
        sc2[sl][col] = acc;
        __syncthreads();
        if (tid < F) cvec[tid] = (sc2[0][tid] + sc2[1][tid]) * (1.0f / (float)N_NODES);
        __syncthreads();
        if (tid < F) {
            float o = b3[tid];
            for (int k = 0; k < F; k++) o += cvec[k] * W3[k * F + tid];
            out[tid] = o;
        }
    }
}

extern "C" void kernel_launch(void* const* d_in, const int* in_sizes, int n_in,
                              void* d_out, int out_size, void* d_ws, size_t ws_size,
                              hipStream_t stream) {
    const float* feat = (const float*)d_in[0];
    const float* W1   = (const float*)d_in[1];
    const float* b1   = (const float*)d_in[2];
    const float* W2   = (const float*)d_in[3];
    const float* b2   = (const float*)d_in[4];
    const float* W3   = (const float*)d_in[5];
    const float* b3   = (const float*)d_in[6];
    const int*   src  = (const int*)d_in[7];
    const int*   dst  = (const int*)d_in[8];
    float* out = (float*)d_out;

    // workspace layout (~68 MB, 16B-aligned blocks first)
    char* ws = (char*)d_ws;
    size_t off = 0;
    uint4* mb    = (uint4*)(ws + off); off += (size_t)N_NODES * F * 2;       // 12.8 MB bf16
    float* Tq    = (float*)(ws + off); off += (size_t)CH * N_NODES * 4;      // 12.8 MB
    int*   P     = (int*)  (ws + off); off += (size_t)CH * N_NODES * 4;      // 12.8 MB
    unsigned short* Hs16 = (unsigned short*)(ws + off); off += (size_t)CH * N_NODES * 2;  // 6.4 MB
    unsigned short* Hd16 = (unsigned short*)(ws + off); off += (size_t)CH * N_NODES * 2;  // 6.4 MB
    uint2* xq    = (uint2*)(ws + off); off += (size_t)N_NODES * F;           // 6.4 MB fp8
    uint2* hq    = (uint2*)(ws + off); off += (size_t)N_NODES * F;           // 6.4 MB fp8
    unsigned short* Wt_hi = (unsigned short*)(ws + off); off += 2 * F * F * 2;
    unsigned short* Wt_lo = (unsigned short*)(ws + off); off += 2 * F * F * 2;
    float* part2 = (float*)(ws + off); off += (size_t)RED_NB * F * 4;        // 131 KB
    int*   esrc  = (int*)  (ws + off); off += (size_t)N_EDGES * 4;           // 3.2 MB
    float* onorm = (float*)(ws + off); off += N_NODES * 4;
    float* inorm = (float*)(ws + off); off += N_NODES * 4;
    float* qt    = (float*)(ws + off); off += N_NODES * 4;
    int*   degd  = (int*)  (ws + off); off += N_NODES * 4;
    int*   rowst = (int*)  (ws + off); off += (N_NODES + 1) * 4;
    int*   bsums = (int*)  (ws + off); off += 64 * 4;

    const int GB = (N_NODES + 63) / 64;          // 782 (store row-guarded)

    // K1: cooperative build (hist/reduceN/tq/scanC/scatter + cvt/wprep tail)
    {
        void* args[] = {(void*)&src, (void*)&dst, (void*)&Hs16, (void*)&Hd16,
                        (void*)&onorm, (void*)&inorm, (void*)&degd, (void*)&bsums,
                        (void*)&rowst, (void*)&P, (void*)&Tq, (void*)&qt,
                        (void*)&esrc, (void*)&feat, (void*)&xq,
                        (void*)&W1, (void*)&W2, (void*)&Wt_hi, (void*)&Wt_lo};
        hipLaunchCooperativeKernel((void*)build_kernel, dim3(4 * CH), dim3(1024),
                                   args, 0, stream);
    }

    // K2/K3: layer 1
    agg_csr_kernel<<<AGG_NB, 256, 0, stream>>>(xq, mb, rowst, esrc, inorm);
    mfma_gemm_kernel<<<GB, 256, 0, stream>>>((const unsigned short*)mb, Wt_hi, Wt_lo, b1,
                                             onorm, (unsigned char*)hq);
    // K4/K5: layer 2
    agg_csr_kernel<<<AGG_NB, 256, 0, stream>>>(hq, mb, rowst, esrc, inorm);
    mfma_gemm_kernel<<<GB, 256, 0, stream>>>((const unsigned short*)mb, Wt_hi + F * F,
                                             Wt_lo + F * F, b2, onorm, (unsigned char*)xq);

    // K6: cooperative epilogue (colsum -> final)
    {
        const unsigned short* x8 = (const unsigned short*)xq;
        void* args[] = {(void*)&x8, (void*)&qt, (void*)&part2,
                        (void*)&W3, (void*)&b3, (void*)&out};
        hipLaunchCooperativeKernel((void*)epi_kernel, dim3(RED_NB), dim3(256),
                                   args, 0, stream);
    }
}

// Round 12
// 289.187 us; speedup vs baseline: 1.5312x; 1.5312x over previous
//
#include <hip/hip_runtime.h>

// GCN: 3-layer GraphConv (norm='both') + mean over nodes.
// Round 12: round-10 structure restored (cooperative experiment reverted).
// Changes vs round 10: scanB inlined into scanC; cvt+wprep merged; CH=32
// (halves partial-array traffic); agg gathers via uint4 (8 lanes/edge,
// half the VMEM instructions).
#define N_NODES 50000
#define N_EDGES 800000
#define F 128
#define SCAN_NB 49      // ceil(50000/1024)
#define CH 32           // edge chunks (EPC=25000 < 65536 keeps ushort hists)
#define EPC (N_EDGES / CH)   // 25000 edges per chunk
#define HALF 25000      // node half-range (packed 16-bit hist)
#define QTR 12500       // node quarter-range (cursors / float bins)
#define BSTRIDE 17      // uint4 per LDS row (odd -> conflict-free ds_read_b128)
#define AGG_NB (N_NODES / 4)   // 12500 agg blocks (4 waves, 1 row/wave)
#define RED_NB 256      // column-partial blocks

typedef __bf16 bf16x8 __attribute__((ext_vector_type(8)));
typedef float  f32x4  __attribute__((ext_vector_type(4)));
typedef float  f32x2  __attribute__((ext_vector_type(2)));

__device__ inline unsigned short f2bf(float f) {  // RNE fp32 -> bf16 bits
    unsigned u = __float_as_uint(f);
    u += 0x7FFF + ((u >> 16) & 1);
    return (unsigned short)(u >> 16);
}
__device__ inline unsigned packbf2(float a, float b) {
    return (unsigned)f2bf(a) | ((unsigned)f2bf(b) << 16);
}

// ---- fp8 e4m3 (OCP on gfx950) helpers ----
__device__ inline void fp8x16_to_f32(uint4 u, float* f) {
    f32x2 v0 = __builtin_amdgcn_cvt_pk_f32_fp8(u.x, false);
    f32x2 v1 = __builtin_amdgcn_cvt_pk_f32_fp8(u.x, true);
    f32x2 v2 = __builtin_amdgcn_cvt_pk_f32_fp8(u.y, false);
    f32x2 v3 = __builtin_amdgcn_cvt_pk_f32_fp8(u.y, true);
    f32x2 v4 = __builtin_amdgcn_cvt_pk_f32_fp8(u.z, false);
    f32x2 v5 = __builtin_amdgcn_cvt_pk_f32_fp8(u.z, true);
    f32x2 v6 = __builtin_amdgcn_cvt_pk_f32_fp8(u.w, false);
    f32x2 v7 = __builtin_amdgcn_cvt_pk_f32_fp8(u.w, true);
    f[0] = v0.x;  f[1] = v0.y;  f[2] = v1.x;  f[3] = v1.y;
    f[4] = v2.x;  f[5] = v2.y;  f[6] = v3.x;  f[7] = v3.y;
    f[8] = v4.x;  f[9] = v4.y;  f[10] = v5.x; f[11] = v5.y;
    f[12] = v6.x; f[13] = v6.y; f[14] = v7.x; f[15] = v7.y;
}
__device__ inline unsigned f32x4_to_fp8(float a, float b, float c, float d) {
    unsigned r = __builtin_amdgcn_cvt_pk_fp8_f32(a, b, 0, false);
    r = __builtin_amdgcn_cvt_pk_fp8_f32(c, d, r, true);
    return r;
}

// ---- chunked histograms -> ushort partials: block = (chunk, type, half) ----
__global__ __launch_bounds__(1024) void hist_kernel(const int* __restrict__ src,
                                                    const int* __restrict__ dst,
                                                    unsigned short* __restrict__ Hs16,
                                                    unsigned short* __restrict__ Hd16) {
    __shared__ unsigned hist[HALF / 2];  // 50 KB
    int bx = blockIdx.x;                 // 4*CH = 128 blocks
    int c = bx >> 2, t = bx & 1, h = (bx >> 1) & 1;
    const int* ids = t ? dst : src;
    unsigned short* H = t ? Hd16 : Hs16;
    int base = h * HALF;
    for (int j = threadIdx.x; j < HALF / 2; j += 1024) hist[j] = 0;
    __syncthreads();
    int e0 = c * EPC;
    for (int e = e0 + threadIdx.x; e < e0 + EPC; e += 1024) {
        int id = ids[e] - base;
        if ((unsigned)id < (unsigned)HALF)
            atomicAdd(&hist[id >> 1], 1u << ((id & 1) * 16));
    }
    __syncthreads();
    for (int j = threadIdx.x; j < HALF / 2; j += 1024)
        *(unsigned*)&H[(size_t)c * N_NODES + base + 2 * j] = hist[j];
}

// ---- reduce partial hists -> norms, degd; block sums for the scan ----
__global__ __launch_bounds__(1024) void reduceN_kernel(const unsigned short* __restrict__ Hs16,
                                                       const unsigned short* __restrict__ Hd16,
                                                       float* __restrict__ onorm,
                                                       float* __restrict__ inorm,
                                                       int* __restrict__ degd,
                                                       int* __restrict__ bsums) {
    __shared__ int wsum[16];
    int i = blockIdx.x * 1024 + threadIdx.x;
    int dd = 0;
    if (i < N_NODES) {
        int ds = 0;
        for (int c = 0; c < CH; c++) {
            ds += Hs16[(size_t)c * N_NODES + i];
            dd += Hd16[(size_t)c * N_NODES + i];
        }
        onorm[i] = rsqrtf(fmaxf((float)ds, 1.0f));
        inorm[i] = rsqrtf(fmaxf((float)dd, 1.0f));
        degd[i] = dd;
    }
    int v = dd;
#pragma unroll
    for (int off = 32; off; off >>= 1) v += __shfl_down(v, off);
    if ((threadIdx.x & 63) == 0) wsum[threadIdx.x >> 6] = v;
    __syncthreads();
    if (threadIdx.x == 0) {
        int s = 0;
#pragma unroll
        for (int k = 0; k < 16; k++) s += wsum[k];
        bsums[blockIdx.x] = s;
    }
}

// ---- t[s] = sum_{e:src=s} inorm[dst(e)]: chunked LDS float bins ----
__global__ __launch_bounds__(1024) void tq_kernel(const int* __restrict__ src,
                                                  const int* __restrict__ dst,
                                                  const float* __restrict__ inorm,
                                                  float* __restrict__ Tq) {
    __shared__ float a[QTR];  // 50 KB
    int bx = blockIdx.x;      // 4*CH = 128 blocks
    int c = bx >> 2, q = bx & 3;
    int base = q * QTR;
    for (int j = threadIdx.x; j < QTR; j += 1024) a[j] = 0.0f;
    __syncthreads();
    int e0 = c * EPC;
    for (int e = e0 + threadIdx.x; e < e0 + EPC; e += 1024) {
        int s = src[e] - base;
        if ((unsigned)s < (unsigned)QTR)
            atomicAdd(&a[s], inorm[dst[e]]);   // LDS float atomic (ds_add_f32)
    }
    __syncthreads();
    for (int j = threadIdx.x; j < QTR; j += 1024)
        Tq[(size_t)c * N_NODES + base + j] = a[j];
}

// ---- scanC: rowst + inline scanB + colpref (Hd16 -> P) + qt ----
__global__ __launch_bounds__(1024) void scanC_kernel(const int* __restrict__ deg,
                                                     const int* __restrict__ bsums,
                                                     int* __restrict__ rowst,
                                                     const unsigned short* __restrict__ Hd16,
                                                     int* __restrict__ P,
                                                     const float* __restrict__ Tq,
                                                     float* __restrict__ qt) {
    __shared__ int wsum[16];
    int t = threadIdx.x, lane = t & 63, w = t >> 6;
    int i = blockIdx.x * 1024 + t;
    int v = (i < N_NODES) ? deg[i] : 0;
    int incl = v;
#pragma unroll
    for (int off = 1; off < 64; off <<= 1) {
        int u = __shfl_up(incl, off);
        if (lane >= off) incl += u;
    }
    if (lane == 63) wsum[w] = incl;
    __syncthreads();
    if (t == 0) {
        int s = 0;                         // inline scanB: prefix of bsums
        for (int k = 0; k < (int)blockIdx.x; k++) s += bsums[k];
#pragma unroll
        for (int k = 0; k < 16; k++) { int x = wsum[k]; wsum[k] = s; s += x; }
    }
    __syncthreads();
    incl += wsum[w];
    if (i < N_NODES) {
        int s = incl - v;          // exclusive prefix
        rowst[i] = s;
        if (i == N_NODES - 1) rowst[N_NODES] = incl;
        float tsum = 0.0f;
        for (int c = 0; c < CH; c++) {
            size_t o = (size_t)c * N_NODES + i;
            P[o] = s; s += Hd16[o];
            tsum += Tq[o];
        }
        qt[i] = tsum;              // xq3 is onorm-prescaled, so q == t
    }
}

// ---- atomic-free scatter: block = (chunk, quarter); writes bare src int ----
__global__ __launch_bounds__(1024) void scatter2_kernel(const int* __restrict__ src,
                                                        const int* __restrict__ dst,
                                                        const int* __restrict__ P,
                                                        int* __restrict__ esrc) {
    __shared__ int cur[QTR];  // 50 KB
    int bx = blockIdx.x;      // 4*CH = 128 blocks
    int c = bx >> 2, q = bx & 3;
    int base = q * QTR;
    for (int j = threadIdx.x; j < QTR; j += 1024)
        cur[j] = P[(size_t)c * N_NODES + base + j];
    __syncthreads();
    int e0 = c * EPC;
    for (int e = e0 + threadIdx.x; e < e0 + EPC; e += 1024) {
        int d = dst[e] - base;
        if ((unsigned)d < (unsigned)QTR) {
            int pos = atomicAdd(&cur[d], 1);   // LDS atomic only
            esrc[pos] = src[e];
        }
    }
}

// ---- prep: cvt (feat*onorm -> fp8 xq) + wprep (W -> n-major bf16 hi/lo) ----
__global__ __launch_bounds__(256) void prep_kernel(const float* __restrict__ feat,
                                                   const float* __restrict__ onorm,
                                                   uint2* __restrict__ xq,
                                                   const float* __restrict__ W1,
                                                   const float* __restrict__ W2,
                                                   unsigned short* __restrict__ Wt_hi,
                                                   unsigned short* __restrict__ Wt_lo) {
    int T = gridDim.x * 256;
    int id0 = blockIdx.x * 256 + threadIdx.x;
    for (int i = id0; i < N_NODES * F / 8; i += T) {
        float w = onorm[i >> 4];   // 16 uint2 per 128-col row
        const float4* xv = (const float4*)feat;
        float4 v0 = xv[i * 2], v1 = xv[i * 2 + 1];
        uint2 o;
        o.x = f32x4_to_fp8(v0.x * w, v0.y * w, v0.z * w, v0.w * w);
        o.y = f32x4_to_fp8(v1.x * w, v1.y * w, v1.z * w, v1.w * w);
        xq[i] = o;
    }
    for (int i = id0; i < 2 * F * F; i += T) {
        int wi = i >> 14, rem = i & 16383;
        int n = rem >> 7, k = rem & 127;
        const float* W = wi ? W2 : W1;
        float v = W[k * F + n];
        unsigned short hi = f2bf(v);
        float r = v - __uint_as_float((unsigned)hi << 16);
        size_t o = (size_t)wi * F * F + (size_t)n * F + k;
        Wt_hi[o] = hi;
        Wt_lo[o] = f2bf(r);
    }
}

// ---- aggregation: 4 waves/block, 1 dst row/wave; 8 lanes/edge uint4 fp8 ----
// group g in [0,8) handles edges e+g / e+8+g; lane t in [0,8) covers cols
// [16t..16t+16) via one uint4 load. 16 edges per iteration, 2 loads/lane.
__global__ __launch_bounds__(256) void agg_csr_kernel(const uint4* __restrict__ xq4,
                                                      uint4* __restrict__ mb,
                                                      const int* __restrict__ rowst,
                                                      const int* __restrict__ esrc,
                                                      const float* __restrict__ inorm) {
    int w = threadIdx.x >> 6;
    int lane = threadIdx.x & 63;
    int g = lane >> 3, t = lane & 7;
    int row = blockIdx.x * 4 + w;
    int beg = __builtin_amdgcn_readfirstlane(rowst[row]);
    int end = __builtin_amdgcn_readfirstlane(rowst[row + 1]);
    float acc[16];
#pragma unroll
    for (int k = 0; k < 16; k++) acc[k] = 0.0f;

    for (int e = beg; e < end; e += 16) {   // clamped, no serial tail
        int ea = min(e + g,     end - 1);
        int eb = min(e + 8 + g, end - 1);
        int sa = esrc[ea], sb = esrc[eb];
        uint4 ua = xq4[(size_t)sa * 8 + t];
        uint4 ub = xq4[(size_t)sb * 8 + t];
        float wa = (e + g     < end) ? 1.0f : 0.0f;
        float wb = (e + 8 + g < end) ? 1.0f : 0.0f;
        float fa[16], fb[16];
        fp8x16_to_f32(ua, fa);
        fp8x16_to_f32(ub, fb);
#pragma unroll
        for (int k = 0; k < 16; k++)
            acc[k] += fa[k] * wa + fb[k] * wb;
    }
#pragma unroll
    for (int k = 0; k < 16; k++) {
        acc[k] += __shfl_xor(acc[k], 8, 64);
        acc[k] += __shfl_xor(acc[k], 16, 64);
        acc[k] += __shfl_xor(acc[k], 32, 64);
    }
    if (g == 0) {
        float inw = inorm[row];
        uint4 o1, o2;
        o1.x = packbf2(acc[0] * inw,  acc[1] * inw);
        o1.y = packbf2(acc[2] * inw,  acc[3] * inw);
        o1.z = packbf2(acc[4] * inw,  acc[5] * inw);
        o1.w = packbf2(acc[6] * inw,  acc[7] * inw);
        o2.x = packbf2(acc[8] * inw,  acc[9] * inw);
        o2.y = packbf2(acc[10] * inw, acc[11] * inw);
        o2.z = packbf2(acc[12] * inw, acc[13] * inw);
        o2.w = packbf2(acc[14] * inw, acc[15] * inw);
        mb[(size_t)row * 16 + t * 2]     = o1;
        mb[(size_t)row * 16 + t * 2 + 1] = o2;
    }
}

// ---- MFMA GEMM, LDS-staged B: Y8 = fp8(onorm[row] * relu(A@(Whi+Wlo)+b)) ----
__global__ __launch_bounds__(256) void mfma_gemm_kernel(const unsigned short* __restrict__ A,
                                                        const unsigned short* __restrict__ Wt_hi,
                                                        const unsigned short* __restrict__ Wt_lo,
                                                        const float* __restrict__ bias,
                                                        const float* __restrict__ onorm,
                                                        unsigned char* __restrict__ Y8) {
    __shared__ uint4 sB[F * BSTRIDE];   // 34816 B
    int tid = threadIdx.x;
    int w = tid >> 6;
    int lane = tid & 63;
    int quad = lane >> 4, r16 = lane & 15;
    int row0 = blockIdx.x * 64 + w * 16;

    const uint4* Arow = (const uint4*)(A + (size_t)(row0 + r16) * F);
    uint4 a[4];
#pragma unroll
    for (int kk = 0; kk < 4; kk++) a[kk] = Arow[kk * 4 + quad];

    f32x4 acc[8];
#pragma unroll
    for (int t = 0; t < 8; t++) acc[t] = (f32x4){0.f, 0.f, 0.f, 0.f};

    const uint4* G[2] = {(const uint4*)Wt_hi, (const uint4*)Wt_lo};
#pragma unroll
    for (int ph = 0; ph < 2; ph++) {
        if (ph) __syncthreads();
        for (int j = tid; j < F * 16; j += 256)
            sB[(j >> 4) * BSTRIDE + (j & 15)] = G[ph][j];
        __syncthreads();
#pragma unroll
        for (int kk = 0; kk < 4; kk++) {
            bf16x8 av = __builtin_bit_cast(bf16x8, a[kk]);
#pragma unroll
            for (int t = 0; t < 8; t++) {
                bf16x8 bv = __builtin_bit_cast(bf16x8,
                    sB[(t * 16 + r16) * BSTRIDE + kk * 4 + quad]);
                acc[t] = __builtin_amdgcn_mfma_f32_16x16x32_bf16(av, bv, acc[t], 0, 0, 0);
            }
        }
    }

    float onw[4];
#pragma unroll
    for (int reg = 0; reg < 4; reg++) {
        int row = row0 + quad * 4 + reg;
        onw[reg] = (row < N_NODES) ? onorm[row] : 0.0f;
    }
#pragma unroll
    for (int t = 0; t < 8; t++) {
        int col = t * 16 + r16;
        float bb = bias[col];
#pragma unroll
        for (int reg = 0; reg < 4; reg++) {
            int row = row0 + quad * 4 + reg;
            if (row < N_NODES) {
                float v = fmaxf(acc[t][reg] + bb, 0.0f) * onw[reg];
                unsigned p = __builtin_amdgcn_cvt_pk_fp8_f32(v, v, 0, false);
                Y8[(size_t)row * F + col] = (unsigned char)(p & 0xFF);
            }
        }
    }
}

// ---- layer-3 collapse: part2[b][j] = sum_rows qt[r] * fp8dec(xq3[r][j]) ----
__global__ __launch_bounds__(256) void colsum_kernel(const unsigned short* __restrict__ x8,
                                                     const float* __restrict__ qt,
                                                     float* __restrict__ part2) {
    __shared__ float sP[4][F];  // 2 KB
    int tid = threadIdx.x;
    int w = tid >> 6, lane = tid & 63;
    float a0 = 0.0f, a1 = 0.0f;
    for (int r = blockIdx.x * 4 + w; r < N_NODES; r += RED_NB * 4) {
        float q = qt[r];
        unsigned us = x8[(size_t)r * 64 + lane];   // 2 fp8 bytes
        f32x2 v = __builtin_amdgcn_cvt_pk_f32_fp8(us, false);
        a0 += v.x * q; a1 += v.y * q;
    }
    sP[w][lane * 2] = a0; sP[w][lane * 2 + 1] = a1;
    __syncthreads();
    if (tid < F)
        part2[(size_t)blockIdx.x * F + tid] =
            sP[0][tid] + sP[1][tid] + sP[2][tid] + sP[3][tid];
}

// ---- final: c = (1/N) * sum_b part2[b], out = c @ W3 + b3 ----
__global__ __launch_bounds__(1024) void final_kernel(const float* __restrict__ part2,
                                                     const float* __restrict__ W3,
                                                     const float* __restrict__ b3,
                                                     float* __restrict__ out) {
    __shared__ float sc[8][F];  // 4 KB
    int tid = threadIdx.x;
    int col = tid & 127, sl = tid >> 7;
    float acc = 0.0f;
    for (int b = sl; b < RED_NB; b += 8) acc += part2[(size_t)b * F + col];
    sc[sl][col] = acc;
    __syncthreads();
    if (tid < F) {
        float s = 0.0f;
#pragma unroll
        for (int k = 0; k < 8; k++) s += sc[k][tid];
        sc[0][tid] = s * (1.0f / (float)N_NODES);
    }
    __syncthreads();
    if (tid < F) {
        float o = b3[tid];
        for (int k = 0; k < F; k++) o += sc[0][k] * W3[k * F + tid];
        out[tid] = o;
    }
}

extern "C" void kernel_launch(void* const* d_in, const int* in_sizes, int n_in,
                              void* d_out, int out_size, void* d_ws, size_t ws_size,
                              hipStream_t stream) {
    const float* feat = (const float*)d_in[0];
    const float* W1   = (const float*)d_in[1];
    const float* b1   = (const float*)d_in[2];
    const float* W2   = (const float*)d_in[3];
    const float* b2   = (const float*)d_in[4];
    const float* W3   = (const float*)d_in[5];
    const float* b3   = (const float*)d_in[6];
    const int*   src  = (const int*)d_in[7];
    const int*   dst  = (const int*)d_in[8];
    float* out = (float*)d_out;

    // workspace layout (~50 MB, 16B-aligned blocks first)
    char* ws = (char*)d_ws;
    size_t off = 0;
    uint4* mb    = (uint4*)(ws + off); off += (size_t)N_NODES * F * 2;       // 12.8 MB bf16
    float* Tq    = (float*)(ws + off); off += (size_t)CH * N_NODES * 4;      // 6.4 MB
    int*   P     = (int*)  (ws + off); off += (size_t)CH * N_NODES * 4;      // 6.4 MB
    unsigned short* Hs16 = (unsigned short*)(ws + off); off += (size_t)CH * N_NODES * 2;  // 3.2 MB
    unsigned short* Hd16 = (unsigned short*)(ws + off); off += (size_t)CH * N_NODES * 2;  // 3.2 MB
    uint2* xq    = (uint2*)(ws + off); off += (size_t)N_NODES * F;           // 6.4 MB fp8
    uint2* hq    = (uint2*)(ws + off); off += (size_t)N_NODES * F;           // 6.4 MB fp8
    unsigned short* Wt_hi = (unsigned short*)(ws + off); off += 2 * F * F * 2;
    unsigned short* Wt_lo = (unsigned short*)(ws + off); off += 2 * F * F * 2;
    float* part2 = (float*)(ws + off); off += (size_t)RED_NB * F * 4;        // 131 KB
    int*   esrc  = (int*)  (ws + off); off += (size_t)N_EDGES * 4;           // 3.2 MB
    float* onorm = (float*)(ws + off); off += N_NODES * 4;
    float* inorm = (float*)(ws + off); off += N_NODES * 4;
    float* qt    = (float*)(ws + off); off += N_NODES * 4;
    int*   degd  = (int*)  (ws + off); off += N_NODES * 4;
    int*   rowst = (int*)  (ws + off); off += (N_NODES + 1) * 4;
    int*   bsums = (int*)  (ws + off); off += 64 * 4;

    const int GB = (N_NODES + 63) / 64;          // 782 (store row-guarded)

    // CSR build + t[s] — zero global atomics, zero memsets
    hist_kernel<<<4 * CH, 1024, 0, stream>>>(src, dst, Hs16, Hd16);
    reduceN_kernel<<<SCAN_NB, 1024, 0, stream>>>(Hs16, Hd16, onorm, inorm, degd, bsums);
    tq_kernel<<<4 * CH, 1024, 0, stream>>>(src, dst, inorm, Tq);
    scanC_kernel<<<SCAN_NB, 1024, 0, stream>>>(degd, bsums, rowst, Hd16, P, Tq, qt);
    scatter2_kernel<<<4 * CH, 1024, 0, stream>>>(src, dst, P, esrc);

    // prep (cvt + wprep merged)
    prep_kernel<<<512, 256, 0, stream>>>(feat, onorm, xq, W1, W2, Wt_hi, Wt_lo);

    // layer 1: agg(xq) -> mb (bf16), gemm -> hq (fp8, onorm-prescaled)
    agg_csr_kernel<<<AGG_NB, 256, 0, stream>>>((const uint4*)xq, mb, rowst, esrc, inorm);
    mfma_gemm_kernel<<<GB, 256, 0, stream>>>((const unsigned short*)mb, Wt_hi, Wt_lo, b1,
                                             onorm, (unsigned char*)hq);
    // layer 2: agg(hq) -> mb, gemm -> xq (reused as xq3)
    agg_csr_kernel<<<AGG_NB, 256, 0, stream>>>((const uint4*)hq, mb, rowst, esrc, inorm);
    mfma_gemm_kernel<<<GB, 256, 0, stream>>>((const unsigned short*)mb, Wt_hi + F * F,
                                             Wt_lo + F * F, b2, onorm, (unsigned char*)xq);
    // layer 3 collapsed: c = (1/N) sum_s t[s]*xq3[s,:]; out = c @ W3 + b3
    colsum_kernel<<<RED_NB, 256, 0, stream>>>((const unsigned short*)xq, qt, part2);
    final_kernel<<<1, 1024, 0, stream>>>(part2, W3, b3, out);
}

// Round 13
// 272.402 us; speedup vs baseline: 1.6256x; 1.0616x over previous
//
#include <hip/hip_runtime.h>

// GCN: 3-layer GraphConv (norm='both') + mean over nodes.
// Round 13: round-10 proven kernel shapes (CH=64, 16-lane uint2 agg) +
// dependency-free fusions: cvt folded into reduceN (onorm in-register),
// wprep as reduceN tail, colsum folded into gemm2 epilogue (xq3 never
// materialized). 14 -> 10 dispatches. Zero global atomics, zero memsets.
#define N_NODES 50000
#define N_EDGES 800000
#define F 128
#define SCAN_NB 49      // ceil(50000/1024)
#define CH 64           // edge chunks (4*CH = 256 blocks = full CU coverage)
#define EPC (N_EDGES / CH)   // 12500 edges per chunk
#define HALF 25000      // node half-range (packed 16-bit hist)
#define QTR 12500       // node quarter-range (cursors / float bins)
#define BSTRIDE 17      // uint4 per LDS row (odd -> conflict-free ds_read_b128)
#define AGG_NB (N_NODES / 4)   // 12500 agg blocks (4 waves, 1 row/wave)
#define GB ((N_NODES + 63) / 64)  // 782 gemm blocks

typedef __bf16 bf16x8 __attribute__((ext_vector_type(8)));
typedef float  f32x4  __attribute__((ext_vector_type(4)));
typedef float  f32x2  __attribute__((ext_vector_type(2)));

__device__ inline unsigned short f2bf(float f) {  // RNE fp32 -> bf16 bits
    unsigned u = __float_as_uint(f);
    u += 0x7FFF + ((u >> 16) & 1);
    return (unsigned short)(u >> 16);
}
__device__ inline unsigned packbf2(float a, float b) {
    return (unsigned)f2bf(a) | ((unsigned)f2bf(b) << 16);
}

// ---- fp8 e4m3 (OCP on gfx950) helpers ----
__device__ inline void fp8x8_to_f32(uint2 u, float* f) {
    f32x2 v0 = __builtin_amdgcn_cvt_pk_f32_fp8(u.x, false);
    f32x2 v1 = __builtin_amdgcn_cvt_pk_f32_fp8(u.x, true);
    f32x2 v2 = __builtin_amdgcn_cvt_pk_f32_fp8(u.y, false);
    f32x2 v3 = __builtin_amdgcn_cvt_pk_f32_fp8(u.y, true);
    f[0] = v0.x; f[1] = v0.y; f[2] = v1.x; f[3] = v1.y;
    f[4] = v2.x; f[5] = v2.y; f[6] = v3.x; f[7] = v3.y;
}
__device__ inline unsigned f32x4_to_fp8(float a, float b, float c, float d) {
    unsigned r = __builtin_amdgcn_cvt_pk_fp8_f32(a, b, 0, false);
    r = __builtin_amdgcn_cvt_pk_fp8_f32(c, d, r, true);
    return r;
}

// ---- chunked histograms -> ushort partials: block = (chunk, type, half) ----
__global__ __launch_bounds__(1024) void hist_kernel(const int* __restrict__ src,
                                                    const int* __restrict__ dst,
                                                    unsigned short* __restrict__ Hs16,
                                                    unsigned short* __restrict__ Hd16) {
    __shared__ unsigned hist[HALF / 2];  // 50 KB
    int bx = blockIdx.x;                 // 256 blocks
    int c = bx >> 2, t = bx & 1, h = (bx >> 1) & 1;
    const int* ids = t ? dst : src;
    unsigned short* H = t ? Hd16 : Hs16;
    int base = h * HALF;
    for (int j = threadIdx.x; j < HALF / 2; j += 1024) hist[j] = 0;
    __syncthreads();
    int e0 = c * EPC;
    for (int e = e0 + threadIdx.x; e < e0 + EPC; e += 1024) {
        int id = ids[e] - base;
        if ((unsigned)id < (unsigned)HALF)
            atomicAdd(&hist[id >> 1], 1u << ((id & 1) * 16));
    }
    __syncthreads();
    for (int j = threadIdx.x; j < HALF / 2; j += 1024)
        *(unsigned*)&H[(size_t)c * N_NODES + base + 2 * j] = hist[j];
}

// ---- reduceN: hist partials -> norms/degd/bsums; + fused cvt (own row,
// onorm in-register) and wprep tail (grid-stride) ----
__global__ __launch_bounds__(1024) void reduceN_kernel(const unsigned short* __restrict__ Hs16,
                                                       const unsigned short* __restrict__ Hd16,
                                                       float* __restrict__ onorm,
                                                       float* __restrict__ inorm,
                                                       int* __restrict__ degd,
                                                       int* __restrict__ bsums,
                                                       const float* __restrict__ feat,
                                                       uint2* __restrict__ xq,
                                                       const float* __restrict__ W1,
                                                       const float* __restrict__ W2,
                                                       unsigned short* __restrict__ Wt_hi,
                                                       unsigned short* __restrict__ Wt_lo) {
    __shared__ int wsum[16];
    int i = blockIdx.x * 1024 + threadIdx.x;
    int dd = 0;
    float onw = 0.0f;
    if (i < N_NODES) {
        int ds = 0;
        for (int c = 0; c < CH; c++) {
            ds += Hs16[(size_t)c * N_NODES + i];
            dd += Hd16[(size_t)c * N_NODES + i];
        }
        onw = rsqrtf(fmaxf((float)ds, 1.0f));
        onorm[i] = onw;
        inorm[i] = rsqrtf(fmaxf((float)dd, 1.0f));
        degd[i] = dd;
    }
    int v = dd;
#pragma unroll
    for (int off = 32; off; off >>= 1) v += __shfl_down(v, off);
    if ((threadIdx.x & 63) == 0) wsum[threadIdx.x >> 6] = v;
    __syncthreads();
    if (threadIdx.x == 0) {
        int s = 0;
#pragma unroll
        for (int k = 0; k < 16; k++) s += wsum[k];
        bsums[blockIdx.x] = s;
    }
    // fused cvt: this thread's row (onorm in register -> no cross-block dep)
    if (i < N_NODES) {
        const float4* fv = (const float4*)feat + (size_t)i * 32;
        uint2* xo = xq + (size_t)i * 16;
#pragma unroll 4
        for (int k = 0; k < 16; k++) {
            float4 v0 = fv[2 * k], v1 = fv[2 * k + 1];
            uint2 o;
            o.x = f32x4_to_fp8(v0.x * onw, v0.y * onw, v0.z * onw, v0.w * onw);
            o.y = f32x4_to_fp8(v1.x * onw, v1.y * onw, v1.z * onw, v1.w * onw);
            xo[k] = o;
        }
    }
    // wprep tail: 32768 elems over 50176 threads
    int id0 = blockIdx.x * 1024 + threadIdx.x;
    if (id0 < 2 * F * F) {
        int wi = id0 >> 14, rem = id0 & 16383;
        int n = rem >> 7, k = rem & 127;
        const float* W = wi ? W2 : W1;
        float v2 = W[k * F + n];
        unsigned short hi = f2bf(v2);
        float r = v2 - __uint_as_float((unsigned)hi << 16);
        size_t o = (size_t)wi * F * F + (size_t)n * F + k;
        Wt_hi[o] = hi;
        Wt_lo[o] = f2bf(r);
    }
}

// ---- t[s] = sum_{e:src=s} inorm[dst(e)]: chunked LDS float bins ----
__global__ __launch_bounds__(1024) void tq_kernel(const int* __restrict__ src,
                                                  const int* __restrict__ dst,
                                                  const float* __restrict__ inorm,
                                                  float* __restrict__ Tq) {
    __shared__ float a[QTR];  // 50 KB
    int bx = blockIdx.x;      // 256 blocks
    int c = bx >> 2, q = bx & 3;
    int base = q * QTR;
    for (int j = threadIdx.x; j < QTR; j += 1024) a[j] = 0.0f;
    __syncthreads();
    int e0 = c * EPC;
    for (int e = e0 + threadIdx.x; e < e0 + EPC; e += 1024) {
        int s = src[e] - base;
        if ((unsigned)s < (unsigned)QTR)
            atomicAdd(&a[s], inorm[dst[e]]);   // LDS float atomic (ds_add_f32)
    }
    __syncthreads();
    for (int j = threadIdx.x; j < QTR; j += 1024)
        Tq[(size_t)c * N_NODES + base + j] = a[j];
}

// ---- scanC: rowst + inline scanB + colpref (Hd16 -> P) + qt ----
__global__ __launch_bounds__(1024) void scanC_kernel(const int* __restrict__ deg,
                                                     const int* __restrict__ bsums,
                                                     int* __restrict__ rowst,
                                                     const unsigned short* __restrict__ Hd16,
                                                     int* __restrict__ P,
                                                     const float* __restrict__ Tq,
                                                     float* __restrict__ qt) {
    __shared__ int wsum[16];
    int t = threadIdx.x, lane = t & 63, w = t >> 6;
    int i = blockIdx.x * 1024 + t;
    int v = (i < N_NODES) ? deg[i] : 0;
    int incl = v;
#pragma unroll
    for (int off = 1; off < 64; off <<= 1) {
        int u = __shfl_up(incl, off);
        if (lane >= off) incl += u;
    }
    if (lane == 63) wsum[w] = incl;
    __syncthreads();
    if (t == 0) {
        int s = 0;                         // inline scanB: prefix of bsums
        for (int k = 0; k < (int)blockIdx.x; k++) s += bsums[k];
#pragma unroll
        for (int k = 0; k < 16; k++) { int x = wsum[k]; wsum[k] = s; s += x; }
    }
    __syncthreads();
    incl += wsum[w];
    if (i < N_NODES) {
        int s = incl - v;          // exclusive prefix
        rowst[i] = s;
        if (i == N_NODES - 1) rowst[N_NODES] = incl;
        float tsum = 0.0f;
        for (int c = 0; c < CH; c++) {
            size_t o = (size_t)c * N_NODES + i;
            P[o] = s; s += Hd16[o];
            tsum += Tq[o];
        }
        qt[i] = tsum;              // xq is onorm-prescaled, so q == t
    }
}

// ---- atomic-free scatter: block = (chunk, quarter); writes bare src int ----
__global__ __launch_bounds__(1024) void scatter2_kernel(const int* __restrict__ src,
                                                        const int* __restrict__ dst,
                                                        const int* __restrict__ P,
                                                        int* __restrict__ esrc) {
    __shared__ int cur[QTR];  // 50 KB
    int bx = blockIdx.x;      // 256 blocks
    int c = bx >> 2, q = bx & 3;
    int base = q * QTR;
    for (int j = threadIdx.x; j < QTR; j += 1024)
        cur[j] = P[(size_t)c * N_NODES + base + j];
    __syncthreads();
    int e0 = c * EPC;
    for (int e = e0 + threadIdx.x; e < e0 + EPC; e += 1024) {
        int d = dst[e] - base;
        if ((unsigned)d < (unsigned)QTR) {
            int pos = atomicAdd(&cur[d], 1);   // LDS atomic only
            esrc[pos] = src[e];
        }
    }
}

// ---- aggregation: 4 waves/block, 1 dst row/wave; 16 lanes/edge fp8 uint2 ----
__global__ __launch_bounds__(256) void agg_csr_kernel(const uint2* __restrict__ xq,
                                                      uint4* __restrict__ mb,
                                                      const int* __restrict__ rowst,
                                                      const int* __restrict__ esrc,
                                                      const float* __restrict__ inorm) {
    int w = threadIdx.x >> 6;
    int lane = threadIdx.x & 63;
    int g = lane >> 4, t = lane & 15;
    int row = blockIdx.x * 4 + w;
    int beg = __builtin_amdgcn_readfirstlane(rowst[row]);
    int end = __builtin_amdgcn_readfirstlane(rowst[row + 1]);
    float acc[8];
#pragma unroll
    for (int k = 0; k < 8; k++) acc[k] = 0.0f;

    for (int e = beg; e < end; e += 16) {   // clamped, 4 gathers in flight
        int ea = min(e + g,      end - 1);
        int eb = min(e + 4 + g,  end - 1);
        int ec = min(e + 8 + g,  end - 1);
        int ed = min(e + 12 + g, end - 1);
        int sa = esrc[ea], sb = esrc[eb], sc = esrc[ec], sd = esrc[ed];
        uint2 ua = xq[(size_t)sa * 16 + t];
        uint2 ub = xq[(size_t)sb * 16 + t];
        uint2 uc = xq[(size_t)sc * 16 + t];
        uint2 ud = xq[(size_t)sd * 16 + t];
        float wa = (e + g      < end) ? 1.0f : 0.0f;
        float wb = (e + 4 + g  < end) ? 1.0f : 0.0f;
        float wc = (e + 8 + g  < end) ? 1.0f : 0.0f;
        float wd = (e + 12 + g < end) ? 1.0f : 0.0f;
        float fa[8], fb[8], fc[8], fd[8];
        fp8x8_to_f32(ua, fa); fp8x8_to_f32(ub, fb);
        fp8x8_to_f32(uc, fc); fp8x8_to_f32(ud, fd);
#pragma unroll
        for (int k = 0; k < 8; k++)
            acc[k] += fa[k] * wa + fb[k] * wb + fc[k] * wc + fd[k] * wd;
    }
#pragma unroll
    for (int k = 0; k < 8; k++) {
        acc[k] += __shfl_xor(acc[k], 16, 64);
        acc[k] += __shfl_xor(acc[k], 32, 64);
    }
    if (g == 0) {
        float inw = inorm[row];
        uint4 o;
        o.x = packbf2(acc[0] * inw, acc[1] * inw);
        o.y = packbf2(acc[2] * inw, acc[3] * inw);
        o.z = packbf2(acc[4] * inw, acc[5] * inw);
        o.w = packbf2(acc[6] * inw, acc[7] * inw);
        mb[(size_t)row * 16 + t] = o;
    }
}

// ---- MFMA GEMM, LDS-staged B ----
// FINAL=0: Y8 = fp8(onorm[row] * relu(A@(Whi+Wlo)+b))  (layer 1)
// FINAL=1: no Y8; part2[block][col] = sum_rows qt[row]*onorm[row]*relu(...)
//          (layer 2 + collapsed layer-3 column sum, fp32 end-to-end)
template <int FINAL>
__global__ __launch_bounds__(256) void mfma_gemm_kernel(const unsigned short* __restrict__ A,
                                                        const unsigned short* __restrict__ Wt_hi,
                                                        const unsigned short* __restrict__ Wt_lo,
                                                        const float* __restrict__ bias,
                                                        const float* __restrict__ onorm,
                                                        unsigned char* __restrict__ Y8,
                                                        const float* __restrict__ qt,
                                                        float* __restrict__ part2) {
    __shared__ uint4 sB[F * BSTRIDE];   // 34816 B
    __shared__ float sPf[4][F];         // 2 KB (FINAL only)
    int tid = threadIdx.x;
    int w = tid >> 6;
    int lane = tid & 63;
    int quad = lane >> 4, r16 = lane & 15;
    int row0 = blockIdx.x * 64 + w * 16;

    const uint4* Arow = (const uint4*)(A + (size_t)(row0 + r16) * F);
    uint4 a[4];
#pragma unroll
    for (int kk = 0; kk < 4; kk++) a[kk] = Arow[kk * 4 + quad];

    f32x4 acc[8];
#pragma unroll
    for (int t = 0; t < 8; t++) acc[t] = (f32x4){0.f, 0.f, 0.f, 0.f};

    const uint4* G[2] = {(const uint4*)Wt_hi, (const uint4*)Wt_lo};
#pragma unroll
    for (int ph = 0; ph < 2; ph++) {
        if (ph) __syncthreads();
        for (int j = tid; j < F * 16; j += 256)
            sB[(j >> 4) * BSTRIDE + (j & 15)] = G[ph][j];
        __syncthreads();
#pragma unroll
        for (int kk = 0; kk < 4; kk++) {
            bf16x8 av = __builtin_bit_cast(bf16x8, a[kk]);
#pragma unroll
            for (int t = 0; t < 8; t++) {
                bf16x8 bv = __builtin_bit_cast(bf16x8,
                    sB[(t * 16 + r16) * BSTRIDE + kk * 4 + quad]);
                acc[t] = __builtin_amdgcn_mfma_f32_16x16x32_bf16(av, bv, acc[t], 0, 0, 0);
            }
        }
    }

    // per-row weights: FINAL ? qt*onorm : onorm
    float rw[4];
#pragma unroll
    for (int reg = 0; reg < 4; reg++) {
        int row = row0 + quad * 4 + reg;
        rw[reg] = (row < N_NODES) ? (FINAL ? qt[row] * onorm[row] : onorm[row]) : 0.0f;
    }

    if (!FINAL) {
#pragma unroll
        for (int t = 0; t < 8; t++) {
            int col = t * 16 + r16;
            float bb = bias[col];
#pragma unroll
            for (int reg = 0; reg < 4; reg++) {
                int row = row0 + quad * 4 + reg;
                if (row < N_NODES) {
                    float v = fmaxf(acc[t][reg] + bb, 0.0f) * rw[reg];
                    unsigned p = __builtin_amdgcn_cvt_pk_fp8_f32(v, v, 0, false);
                    Y8[(size_t)row * F + col] = (unsigned char)(p & 0xFF);
                }
            }
        }
    } else {
        // column partials: p[col] = sum over this wave's 16 rows
#pragma unroll
        for (int t = 0; t < 8; t++) {
            int col = t * 16 + r16;
            float bb = bias[col];
            float p = 0.0f;
#pragma unroll
            for (int reg = 0; reg < 4; reg++)
                p += fmaxf(acc[t][reg] + bb, 0.0f) * rw[reg];
            p += __shfl_xor(p, 16, 64);      // reduce over quad
            p += __shfl_xor(p, 32, 64);
            if (quad == 0) sPf[w][col] = p;
        }
        __syncthreads();
        if (tid < F)
            part2[(size_t)blockIdx.x * F + tid] =
                sPf[0][tid] + sPf[1][tid] + sPf[2][tid] + sPf[3][tid];
    }
}

// ---- final: c = (1/N) * sum_b part2[b] (b < GB), out = c @ W3 + b3 ----
__global__ __launch_bounds__(1024) void final_kernel(const float* __restrict__ part2,
                                                     const float* __restrict__ W3,
                                                     const float* __restrict__ b3,
                                                     float* __restrict__ out) {
    __shared__ float sc[8][F];  // 4 KB
    int tid = threadIdx.x;
    int col = tid & 127, sl = tid >> 7;
    float acc = 0.0f;
    for (int b = sl; b < GB; b += 8) acc += part2[(size_t)b * F + col];
    sc[sl][col] = acc;
    __syncthreads();
    if (tid < F) {
        float s = 0.0f;
#pragma unroll
        for (int k = 0; k < 8; k++) s += sc[k][tid];
        sc[0][tid] = s * (1.0f / (float)N_NODES);
    }
    __syncthreads();
    if (tid < F) {
        float o = b3[tid];
        for (int k = 0; k < F; k++) o += sc[0][k] * W3[k * F + tid];
        out[tid] = o;
    }
}

extern "C" void kernel_launch(void* const* d_in, const int* in_sizes, int n_in,
                              void* d_out, int out_size, void* d_ws, size_t ws_size,
                              hipStream_t stream) {
    const float* feat = (const float*)d_in[0];
    const float* W1   = (const float*)d_in[1];
    const float* b1   = (const float*)d_in[2];
    const float* W2   = (const float*)d_in[3];
    const float* b2   = (const float*)d_in[4];
    const float* W3   = (const float*)d_in[5];
    const float* b3   = (const float*)d_in[6];
    const int*   src  = (const int*)d_in[7];
    const int*   dst  = (const int*)d_in[8];
    float* out = (float*)d_out;

    // workspace layout (~70 MB, 16B-aligned blocks first)
    char* ws = (char*)d_ws;
    size_t off = 0;
    uint4* mb    = (uint4*)(ws + off); off += (size_t)N_NODES * F * 2;       // 12.8 MB bf16
    float* Tq    = (float*)(ws + off); off += (size_t)CH * N_NODES * 4;      // 12.8 MB
    int*   P     = (int*)  (ws + off); off += (size_t)CH * N_NODES * 4;      // 12.8 MB
    unsigned short* Hs16 = (unsigned short*)(ws + off); off += (size_t)CH * N_NODES * 2;  // 6.4 MB
    unsigned short* Hd16 = (unsigned short*)(ws + off); off += (size_t)CH * N_NODES * 2;  // 6.4 MB
    uint2* xq    = (uint2*)(ws + off); off += (size_t)N_NODES * F;           // 6.4 MB fp8
    uint2* hq    = (uint2*)(ws + off); off += (size_t)N_NODES * F;           // 6.4 MB fp8
    unsigned short* Wt_hi = (unsigned short*)(ws + off); off += 2 * F * F * 2;
    unsigned short* Wt_lo = (unsigned short*)(ws + off); off += 2 * F * F * 2;
    float* part2 = (float*)(ws + off); off += (size_t)GB * F * 4;            // 400 KB
    int*   esrc  = (int*)  (ws + off); off += (size_t)N_EDGES * 4;           // 3.2 MB
    float* onorm = (float*)(ws + off); off += N_NODES * 4;
    float* inorm = (float*)(ws + off); off += N_NODES * 4;
    float* qt    = (float*)(ws + off); off += N_NODES * 4;
    int*   degd  = (int*)  (ws + off); off += N_NODES * 4;
    int*   rowst = (int*)  (ws + off); off += (N_NODES + 1) * 4;
    int*   bsums = (int*)  (ws + off); off += 64 * 4;

    // CSR build + t[s] + prep — zero global atomics, zero memsets
    hist_kernel<<<4 * CH, 1024, 0, stream>>>(src, dst, Hs16, Hd16);
    reduceN_kernel<<<SCAN_NB, 1024, 0, stream>>>(Hs16, Hd16, onorm, inorm, degd, bsums,
                                                 feat, xq, W1, W2, Wt_hi, Wt_lo);
    tq_kernel<<<4 * CH, 1024, 0, stream>>>(src, dst, inorm, Tq);
    scanC_kernel<<<SCAN_NB, 1024, 0, stream>>>(degd, bsums, rowst, Hd16, P, Tq, qt);
    scatter2_kernel<<<4 * CH, 1024, 0, stream>>>(src, dst, P, esrc);

    // layer 1: agg(xq) -> mb (bf16), gemm -> hq (fp8, onorm-prescaled)
    agg_csr_kernel<<<AGG_NB, 256, 0, stream>>>(xq, mb, rowst, esrc, inorm);
    mfma_gemm_kernel<0><<<GB, 256, 0, stream>>>((const unsigned short*)mb, Wt_hi, Wt_lo, b1,
                                                onorm, (unsigned char*)hq, qt, part2);
    // layer 2: agg(hq) -> mb, gemm(+fused layer-3 column sum) -> part2
    agg_csr_kernel<<<AGG_NB, 256, 0, stream>>>(hq, mb, rowst, esrc, inorm);
    mfma_gemm_kernel<1><<<GB, 256, 0, stream>>>((const unsigned short*)mb, Wt_hi + F * F,
                                                Wt_lo + F * F, b2, onorm,
                                                (unsigned char*)hq, qt, part2);
    // final: c = (1/N) sum_b part2[b]; out = c @ W3 + b3
    final_kernel<<<1, 1024, 0, stream>>>(part2, W3, b3, out);
}

// Round 14
// 243.182 us; speedup vs baseline: 1.8209x; 1.1202x over previous
//
#include <hip/hip_runtime.h>

// GCN: 3-layer GraphConv (norm='both') + mean over nodes.
// Round 14: round-13 minus the bad fusion. cvt/wprep back to a standalone
// 512-block prep kernel; reduceN re-gridded to 196x256 (full CU coverage).
// Kept: scanB inlined in scanC, colsum fused into gemm2 epilogue (xq3 never
// materialized, layer 3 fp32). Zero global atomics, zero memsets.
#define N_NODES 50000
#define N_EDGES 800000
#define F 128
#define SCAN_NB 49      // scanC blocks: ceil(50000/1024)
#define RN_NB 196       // reduceN blocks: ceil(50000/256)
#define CH 64           // edge chunks (4*CH = 256 blocks = full CU coverage)
#define EPC (N_EDGES / CH)   // 12500 edges per chunk
#define HALF 25000      // node half-range (packed 16-bit hist)
#define QTR 12500       // node quarter-range (cursors / float bins)
#define BSTRIDE 17      // uint4 per LDS row (odd -> conflict-free ds_read_b128)
#define AGG_NB (N_NODES / 4)   // 12500 agg blocks (4 waves, 1 row/wave)
#define GB ((N_NODES + 63) / 64)  // 782 gemm blocks

typedef __bf16 bf16x8 __attribute__((ext_vector_type(8)));
typedef float  f32x4  __attribute__((ext_vector_type(4)));
typedef float  f32x2  __attribute__((ext_vector_type(2)));

__device__ inline unsigned short f2bf(float f) {  // RNE fp32 -> bf16 bits
    unsigned u = __float_as_uint(f);
    u += 0x7FFF + ((u >> 16) & 1);
    return (unsigned short)(u >> 16);
}
__device__ inline unsigned packbf2(float a, float b) {
    return (unsigned)f2bf(a) | ((unsigned)f2bf(b) << 16);
}

// ---- fp8 e4m3 (OCP on gfx950) helpers ----
__device__ inline void fp8x8_to_f32(uint2 u, float* f) {
    f32x2 v0 = __builtin_amdgcn_cvt_pk_f32_fp8(u.x, false);
    f32x2 v1 = __builtin_amdgcn_cvt_pk_f32_fp8(u.x, true);
    f32x2 v2 = __builtin_amdgcn_cvt_pk_f32_fp8(u.y, false);
    f32x2 v3 = __builtin_amdgcn_cvt_pk_f32_fp8(u.y, true);
    f[0] = v0.x; f[1] = v0.y; f[2] = v1.x; f[3] = v1.y;
    f[4] = v2.x; f[5] = v2.y; f[6] = v3.x; f[7] = v3.y;
}
__device__ inline unsigned f32x4_to_fp8(float a, float b, float c, float d) {
    unsigned r = __builtin_amdgcn_cvt_pk_fp8_f32(a, b, 0, false);
    r = __builtin_amdgcn_cvt_pk_fp8_f32(c, d, r, true);
    return r;
}

// ---- chunked histograms -> ushort partials: block = (chunk, type, half) ----
__global__ __launch_bounds__(1024) void hist_kernel(const int* __restrict__ src,
                                                    const int* __restrict__ dst,
                                                    unsigned short* __restrict__ Hs16,
                                                    unsigned short* __restrict__ Hd16) {
    __shared__ unsigned hist[HALF / 2];  // 50 KB
    int bx = blockIdx.x;                 // 256 blocks
    int c = bx >> 2, t = bx & 1, h = (bx >> 1) & 1;
    const int* ids = t ? dst : src;
    unsigned short* H = t ? Hd16 : Hs16;
    int base = h * HALF;
    for (int j = threadIdx.x; j < HALF / 2; j += 1024) hist[j] = 0;
    __syncthreads();
    int e0 = c * EPC;
    for (int e = e0 + threadIdx.x; e < e0 + EPC; e += 1024) {
        int id = ids[e] - base;
        if ((unsigned)id < (unsigned)HALF)
            atomicAdd(&hist[id >> 1], 1u << ((id & 1) * 16));
    }
    __syncthreads();
    for (int j = threadIdx.x; j < HALF / 2; j += 1024)
        *(unsigned*)&H[(size_t)c * N_NODES + base + 2 * j] = hist[j];
}

// ---- reduceN: 196 blocks x 256 thr, one node/thread -> norms/degd/bsums ----
__global__ __launch_bounds__(256) void reduceN_kernel(const unsigned short* __restrict__ Hs16,
                                                      const unsigned short* __restrict__ Hd16,
                                                      float* __restrict__ onorm,
                                                      float* __restrict__ inorm,
                                                      int* __restrict__ degd,
                                                      int* __restrict__ bsums) {
    __shared__ int wsum[4];
    int i = blockIdx.x * 256 + threadIdx.x;
    int dd = 0;
    if (i < N_NODES) {
        int ds = 0;
        for (int c = 0; c < CH; c++) {
            ds += Hs16[(size_t)c * N_NODES + i];
            dd += Hd16[(size_t)c * N_NODES + i];
        }
        onorm[i] = rsqrtf(fmaxf((float)ds, 1.0f));
        inorm[i] = rsqrtf(fmaxf((float)dd, 1.0f));
        degd[i] = dd;
    }
    int v = dd;
#pragma unroll
    for (int off = 32; off; off >>= 1) v += __shfl_down(v, off);
    if ((threadIdx.x & 63) == 0) wsum[threadIdx.x >> 6] = v;
    __syncthreads();
    if (threadIdx.x == 0)
        bsums[blockIdx.x] = wsum[0] + wsum[1] + wsum[2] + wsum[3];
}

// ---- t[s] = sum_{e:src=s} inorm[dst(e)]: chunked LDS float bins ----
__global__ __launch_bounds__(1024) void tq_kernel(const int* __restrict__ src,
                                                  const int* __restrict__ dst,
                                                  const float* __restrict__ inorm,
                                                  float* __restrict__ Tq) {
    __shared__ float a[QTR];  // 50 KB
    int bx = blockIdx.x;      // 256 blocks
    int c = bx >> 2, q = bx & 3;
    int base = q * QTR;
    for (int j = threadIdx.x; j < QTR; j += 1024) a[j] = 0.0f;
    __syncthreads();
    int e0 = c * EPC;
    for (int e = e0 + threadIdx.x; e < e0 + EPC; e += 1024) {
        int s = src[e] - base;
        if ((unsigned)s < (unsigned)QTR)
            atomicAdd(&a[s], inorm[dst[e]]);   // LDS float atomic (ds_add_f32)
    }
    __syncthreads();
    for (int j = threadIdx.x; j < QTR; j += 1024)
        Tq[(size_t)c * N_NODES + base + j] = a[j];
}

// ---- scanC: rowst + inline scan of bsums (4 per scanC block) + colpref + qt ----
__global__ __launch_bounds__(1024) void scanC_kernel(const int* __restrict__ deg,
                                                     const int* __restrict__ bsums,
                                                     int* __restrict__ rowst,
                                                     const unsigned short* __restrict__ Hd16,
                                                     int* __restrict__ P,
                                                     const float* __restrict__ Tq,
                                                     float* __restrict__ qt) {
    __shared__ int wsum[16];
    int t = threadIdx.x, lane = t & 63, w = t >> 6;
    int i = blockIdx.x * 1024 + t;
    int v = (i < N_NODES) ? deg[i] : 0;
    int incl = v;
#pragma unroll
    for (int off = 1; off < 64; off <<= 1) {
        int u = __shfl_up(incl, off);
        if (lane >= off) incl += u;
    }
    if (lane == 63) wsum[w] = incl;
    __syncthreads();
    if (t == 0) {
        int s = 0;                      // inline scanB: 4 reduceN blocks per scanC block
        int kmax = min(4 * (int)blockIdx.x, RN_NB);
        for (int k = 0; k < kmax; k++) s += bsums[k];
#pragma unroll
        for (int k = 0; k < 16; k++) { int x = wsum[k]; wsum[k] = s; s += x; }
    }
    __syncthreads();
    incl += wsum[w];
    if (i < N_NODES) {
        int s = incl - v;          // exclusive prefix
        rowst[i] = s;
        if (i == N_NODES - 1) rowst[N_NODES] = incl;
        float tsum = 0.0f;
        for (int c = 0; c < CH; c++) {
            size_t o = (size_t)c * N_NODES + i;
            P[o] = s; s += Hd16[o];
            tsum += Tq[o];
        }
        qt[i] = tsum;              // xq is onorm-prescaled, so q == t
    }
}

// ---- atomic-free scatter: block = (chunk, quarter); writes bare src int ----
__global__ __launch_bounds__(1024) void scatter2_kernel(const int* __restrict__ src,
                                                        const int* __restrict__ dst,
                                                        const int* __restrict__ P,
                                                        int* __restrict__ esrc) {
    __shared__ int cur[QTR];  // 50 KB
    int bx = blockIdx.x;      // 256 blocks
    int c = bx >> 2, q = bx & 3;
    int base = q * QTR;
    for (int j = threadIdx.x; j < QTR; j += 1024)
        cur[j] = P[(size_t)c * N_NODES + base + j];
    __syncthreads();
    int e0 = c * EPC;
    for (int e = e0 + threadIdx.x; e < e0 + EPC; e += 1024) {
        int d = dst[e] - base;
        if ((unsigned)d < (unsigned)QTR) {
            int pos = atomicAdd(&cur[d], 1);   // LDS atomic only
            esrc[pos] = src[e];
        }
    }
}

// ---- prep: cvt (feat*onorm -> fp8 xq) + wprep (W -> n-major bf16 hi/lo) ----
__global__ __launch_bounds__(256) void prep_kernel(const float* __restrict__ feat,
                                                   const float* __restrict__ onorm,
                                                   uint2* __restrict__ xq,
                                                   const float* __restrict__ W1,
                                                   const float* __restrict__ W2,
                                                   unsigned short* __restrict__ Wt_hi,
                                                   unsigned short* __restrict__ Wt_lo) {
    int T = gridDim.x * 256;
    int id0 = blockIdx.x * 256 + threadIdx.x;
    for (int i = id0; i < N_NODES * F / 8; i += T) {
        float w = onorm[i >> 4];   // 16 uint2 per 128-col row
        const float4* xv = (const float4*)feat;
        float4 v0 = xv[i * 2], v1 = xv[i * 2 + 1];
        uint2 o;
        o.x = f32x4_to_fp8(v0.x * w, v0.y * w, v0.z * w, v0.w * w);
        o.y = f32x4_to_fp8(v1.x * w, v1.y * w, v1.z * w, v1.w * w);
        xq[i] = o;
    }
    for (int i = id0; i < 2 * F * F; i += T) {
        int wi = i >> 14, rem = i & 16383;
        int n = rem >> 7, k = rem & 127;
        const float* W = wi ? W2 : W1;
        float v = W[k * F + n];
        unsigned short hi = f2bf(v);
        float r = v - __uint_as_float((unsigned)hi << 16);
        size_t o = (size_t)wi * F * F + (size_t)n * F + k;
        Wt_hi[o] = hi;
        Wt_lo[o] = f2bf(r);
    }
}

// ---- aggregation: 4 waves/block, 1 dst row/wave; 16 lanes/edge fp8 uint2 ----
__global__ __launch_bounds__(256) void agg_csr_kernel(const uint2* __restrict__ xq,
                                                      uint4* __restrict__ mb,
                                                      const int* __restrict__ rowst,
                                                      const int* __restrict__ esrc,
                                                      const float* __restrict__ inorm) {
    int w = threadIdx.x >> 6;
    int lane = threadIdx.x & 63;
    int g = lane >> 4, t = lane & 15;
    int row = blockIdx.x * 4 + w;
    int beg = __builtin_amdgcn_readfirstlane(rowst[row]);
    int end = __builtin_amdgcn_readfirstlane(rowst[row + 1]);
    float acc[8];
#pragma unroll
    for (int k = 0; k < 8; k++) acc[k] = 0.0f;

    for (int e = beg; e < end; e += 16) {   // clamped, 4 gathers in flight
        int ea = min(e + g,      end - 1);
        int eb = min(e + 4 + g,  end - 1);
        int ec = min(e + 8 + g,  end - 1);
        int ed = min(e + 12 + g, end - 1);
        int sa = esrc[ea], sb = esrc[eb], sc = esrc[ec], sd = esrc[ed];
        uint2 ua = xq[(size_t)sa * 16 + t];
        uint2 ub = xq[(size_t)sb * 16 + t];
        uint2 uc = xq[(size_t)sc * 16 + t];
        uint2 ud = xq[(size_t)sd * 16 + t];
        float wa = (e + g      < end) ? 1.0f : 0.0f;
        float wb = (e + 4 + g  < end) ? 1.0f : 0.0f;
        float wc = (e + 8 + g  < end) ? 1.0f : 0.0f;
        float wd = (e + 12 + g < end) ? 1.0f : 0.0f;
        float fa[8], fb[8], fc[8], fd[8];
        fp8x8_to_f32(ua, fa); fp8x8_to_f32(ub, fb);
        fp8x8_to_f32(uc, fc); fp8x8_to_f32(ud, fd);
#pragma unroll
        for (int k = 0; k < 8; k++)
            acc[k] += fa[k] * wa + fb[k] * wb + fc[k] * wc + fd[k] * wd;
    }
#pragma unroll
    for (int k = 0; k < 8; k++) {
        acc[k] += __shfl_xor(acc[k], 16, 64);
        acc[k] += __shfl_xor(acc[k], 32, 64);
    }
    if (g == 0) {
        float inw = inorm[row];
        uint4 o;
        o.x = packbf2(acc[0] * inw, acc[1] * inw);
        o.y = packbf2(acc[2] * inw, acc[3] * inw);
        o.z = packbf2(acc[4] * inw, acc[5] * inw);
        o.w = packbf2(acc[6] * inw, acc[7] * inw);
        mb[(size_t)row * 16 + t] = o;
    }
}

// ---- MFMA GEMM, LDS-staged B ----
// FINAL=0: Y8 = fp8(onorm[row] * relu(A@(Whi+Wlo)+b))  (layer 1)
// FINAL=1: no Y8; part2[block][col] = sum_rows qt[row]*onorm[row]*relu(...)
template <int FINAL>
__global__ __launch_bounds__(256) void mfma_gemm_kernel(const unsigned short* __restrict__ A,
                                                        const unsigned short* __restrict__ Wt_hi,
                                                        const unsigned short* __restrict__ Wt_lo,
                                                        const float* __restrict__ bias,
                                                        const float* __restrict__ onorm,
                                                        unsigned char* __restrict__ Y8,
                                                        const float* __restrict__ qt,
                                                        float* __restrict__ part2) {
    __shared__ uint4 sB[F * BSTRIDE];   // 34816 B
    __shared__ float sPf[4][F];         // 2 KB (FINAL only)
    int tid = threadIdx.x;
    int w = tid >> 6;
    int lane = tid & 63;
    int quad = lane >> 4, r16 = lane & 15;
    int row0 = blockIdx.x * 64 + w * 16;

    const uint4* Arow = (const uint4*)(A + (size_t)(row0 + r16) * F);
    uint4 a[4];
#pragma unroll
    for (int kk = 0; kk < 4; kk++) a[kk] = Arow[kk * 4 + quad];

    f32x4 acc[8];
#pragma unroll
    for (int t = 0; t < 8; t++) acc[t] = (f32x4){0.f, 0.f, 0.f, 0.f};

    const uint4* G[2] = {(const uint4*)Wt_hi, (const uint4*)Wt_lo};
#pragma unroll
    for (int ph = 0; ph < 2; ph++) {
        if (ph) __syncthreads();
        for (int j = tid; j < F * 16; j += 256)
            sB[(j >> 4) * BSTRIDE + (j & 15)] = G[ph][j];
        __syncthreads();
#pragma unroll
        for (int kk = 0; kk < 4; kk++) {
            bf16x8 av = __builtin_bit_cast(bf16x8, a[kk]);
#pragma unroll
            for (int t = 0; t < 8; t++) {
                bf16x8 bv = __builtin_bit_cast(bf16x8,
                    sB[(t * 16 + r16) * BSTRIDE + kk * 4 + quad]);
                acc[t] = __builtin_amdgcn_mfma_f32_16x16x32_bf16(av, bv, acc[t], 0, 0, 0);
            }
        }
    }

    float rw[4];
#pragma unroll
    for (int reg = 0; reg < 4; reg++) {
        int row = row0 + quad * 4 + reg;
        rw[reg] = (row < N_NODES) ? (FINAL ? qt[row] * onorm[row] : onorm[row]) : 0.0f;
    }

    if (!FINAL) {
#pragma unroll
        for (int t = 0; t < 8; t++) {
            int col = t * 16 + r16;
            float bb = bias[col];
#pragma unroll
            for (int reg = 0; reg < 4; reg++) {
                int row = row0 + quad * 4 + reg;
                if (row < N_NODES) {
                    float v = fmaxf(acc[t][reg] + bb, 0.0f) * rw[reg];
                    unsigned p = __builtin_amdgcn_cvt_pk_fp8_f32(v, v, 0, false);
                    Y8[(size_t)row * F + col] = (unsigned char)(p & 0xFF);
                }
            }
        }
    } else {
#pragma unroll
        for (int t = 0; t < 8; t++) {
            int col = t * 16 + r16;
            float bb = bias[col];
            float p = 0.0f;
#pragma unroll
            for (int reg = 0; reg < 4; reg++)
                p += fmaxf(acc[t][reg] + bb, 0.0f) * rw[reg];
            p += __shfl_xor(p, 16, 64);      // reduce over quad
            p += __shfl_xor(p, 32, 64);
            if (quad == 0) sPf[w][col] = p;
        }
        __syncthreads();
        if (tid < F)
            part2[(size_t)blockIdx.x * F + tid] =
                sPf[0][tid] + sPf[1][tid] + sPf[2][tid] + sPf[3][tid];
    }
}

// ---- final: c = (1/N) * sum_b part2[b] (b < GB), out = c @ W3 + b3 ----
__global__ __launch_bounds__(1024) void final_kernel(const float* __restrict__ part2,
                                                     const float* __restrict__ W3,
                                                     const float* __restrict__ b3,
                                                     float* __restrict__ out) {
    __shared__ float sc[8][F];  // 4 KB
    int tid = threadIdx.x;
    int col = tid & 127, sl = tid >> 7;
    float acc = 0.0f;
    for (int b = sl; b < GB; b += 8) acc += part2[(size_t)b * F + col];
    sc[sl][col] = acc;
    __syncthreads();
    if (tid < F) {
        float s = 0.0f;
#pragma unroll
        for (int k = 0; k < 8; k++) s += sc[k][tid];
        sc[0][tid] = s * (1.0f / (float)N_NODES);
    }
    __syncthreads();
    if (tid < F) {
        float o = b3[tid];
        for (int k = 0; k < F; k++) o += sc[0][k] * W3[k * F + tid];
        out[tid] = o;
    }
}

extern "C" void kernel_launch(void* const* d_in, const int* in_sizes, int n_in,
                              void* d_out, int out_size, void* d_ws, size_t ws_size,
                              hipStream_t stream) {
    const float* feat = (const float*)d_in[0];
    const float* W1   = (const float*)d_in[1];
    const float* b1   = (const float*)d_in[2];
    const float* W2   = (const float*)d_in[3];
    const float* b2   = (const float*)d_in[4];
    const float* W3   = (const float*)d_in[5];
    const float* b3   = (const float*)d_in[6];
    const int*   src  = (const int*)d_in[7];
    const int*   dst  = (const int*)d_in[8];
    float* out = (float*)d_out;

    // workspace layout (~70 MB, 16B-aligned blocks first)
    char* ws = (char*)d_ws;
    size_t off = 0;
    uint4* mb    = (uint4*)(ws + off); off += (size_t)N_NODES * F * 2;       // 12.8 MB bf16
    float* Tq    = (float*)(ws + off); off += (size_t)CH * N_NODES * 4;      // 12.8 MB
    int*   P     = (int*)  (ws + off); off += (size_t)CH * N_NODES * 4;      // 12.8 MB
    unsigned short* Hs16 = (unsigned short*)(ws + off); off += (size_t)CH * N_NODES * 2;  // 6.4 MB
    unsigned short* Hd16 = (unsigned short*)(ws + off); off += (size_t)CH * N_NODES * 2;  // 6.4 MB
    uint2* xq    = (uint2*)(ws + off); off += (size_t)N_NODES * F;           // 6.4 MB fp8
    uint2* hq    = (uint2*)(ws + off); off += (size_t)N_NODES * F;           // 6.4 MB fp8
    unsigned short* Wt_hi = (unsigned short*)(ws + off); off += 2 * F * F * 2;
    unsigned short* Wt_lo = (unsigned short*)(ws + off); off += 2 * F * F * 2;
    float* part2 = (float*)(ws + off); off += (size_t)GB * F * 4;            // 400 KB
    int*   esrc  = (int*)  (ws + off); off += (size_t)N_EDGES * 4;           // 3.2 MB
    float* onorm = (float*)(ws + off); off += N_NODES * 4;
    float* inorm = (float*)(ws + off); off += N_NODES * 4;
    float* qt    = (float*)(ws + off); off += N_NODES * 4;
    int*   degd  = (int*)  (ws + off); off += N_NODES * 4;
    int*   rowst = (int*)  (ws + off); off += (N_NODES + 1) * 4;
    int*   bsums = (int*)  (ws + off); off += 256 * 4;

    // CSR build + t[s] — zero global atomics, zero memsets
    hist_kernel<<<4 * CH, 1024, 0, stream>>>(src, dst, Hs16, Hd16);
    reduceN_kernel<<<RN_NB, 256, 0, stream>>>(Hs16, Hd16, onorm, inorm, degd, bsums);
    tq_kernel<<<4 * CH, 1024, 0, stream>>>(src, dst, inorm, Tq);
    scanC_kernel<<<SCAN_NB, 1024, 0, stream>>>(degd, bsums, rowst, Hd16, P, Tq, qt);
    scatter2_kernel<<<4 * CH, 1024, 0, stream>>>(src, dst, P, esrc);

    // prep (cvt + wprep, full-machine grid)
    prep_kernel<<<512, 256, 0, stream>>>(feat, onorm, xq, W1, W2, Wt_hi, Wt_lo);

    // layer 1: agg(xq) -> mb (bf16), gemm -> hq (fp8, onorm-prescaled)
    agg_csr_kernel<<<AGG_NB, 256, 0, stream>>>(xq, mb, rowst, esrc, inorm);
    mfma_gemm_kernel<0><<<GB, 256, 0, stream>>>((const unsigned short*)mb, Wt_hi, Wt_lo, b1,
                                                onorm, (unsigned char*)hq, qt, part2);
    // layer 2: agg(hq) -> mb, gemm(+fused layer-3 column sum) -> part2
    agg_csr_kernel<<<AGG_NB, 256, 0, stream>>>(hq, mb, rowst, esrc, inorm);
    mfma_gemm_kernel<1><<<GB, 256, 0, stream>>>((const unsigned short*)mb, Wt_hi + F * F,
                                                Wt_lo + F * F, b2, onorm,
                                                (unsigned char*)hq, qt, part2);
    // final: c = (1/N) sum_b part2[b]; out = c @ W3 + b3
    final_kernel<<<1, 1024, 0, stream>>>(part2, W3, b3, out);
}

// Round 15
// 233.040 us; speedup vs baseline: 1.9001x; 1.0435x over previous
//
#include <hip/hip_runtime.h>

// GCN: 3-layer GraphConv (norm='both') + mean over nodes.
// Round 15: round-14 + (a) prep fused into tq's tail (full-machine 256x1024
// grid — unlike R13's failed 49-block fusion), (b) single-bf16 W (dropped
// W_lo): gemm is one staging phase + 64 MFMA. Kept: scanB inline in scanC,
// colsum fused in gemm2 epilogue. Zero global atomics, zero memsets.
#define N_NODES 50000
#define N_EDGES 800000
#define F 128
#define SCAN_NB 49      // scanC blocks: ceil(50000/1024)
#define RN_NB 196       // reduceN blocks: ceil(50000/256)
#define CH 64           // edge chunks (4*CH = 256 blocks = full CU coverage)
#define EPC (N_EDGES / CH)   // 12500 edges per chunk
#define HALF 25000      // node half-range (packed 16-bit hist)
#define QTR 12500       // node quarter-range (cursors / float bins)
#define BSTRIDE 17      // uint4 per LDS row (odd -> conflict-free ds_read_b128)
#define AGG_NB (N_NODES / 4)   // 12500 agg blocks (4 waves, 1 row/wave)
#define GB ((N_NODES + 63) / 64)  // 782 gemm blocks

typedef __bf16 bf16x8 __attribute__((ext_vector_type(8)));
typedef float  f32x4  __attribute__((ext_vector_type(4)));
typedef float  f32x2  __attribute__((ext_vector_type(2)));

__device__ inline unsigned short f2bf(float f) {  // RNE fp32 -> bf16 bits
    unsigned u = __float_as_uint(f);
    u += 0x7FFF + ((u >> 16) & 1);
    return (unsigned short)(u >> 16);
}
__device__ inline unsigned packbf2(float a, float b) {
    return (unsigned)f2bf(a) | ((unsigned)f2bf(b) << 16);
}

// ---- fp8 e4m3 (OCP on gfx950) helpers ----
__device__ inline void fp8x8_to_f32(uint2 u, float* f) {
    f32x2 v0 = __builtin_amdgcn_cvt_pk_f32_fp8(u.x, false);
    f32x2 v1 = __builtin_amdgcn_cvt_pk_f32_fp8(u.x, true);
    f32x2 v2 = __builtin_amdgcn_cvt_pk_f32_fp8(u.y, false);
    f32x2 v3 = __builtin_amdgcn_cvt_pk_f32_fp8(u.y, true);
    f[0] = v0.x; f[1] = v0.y; f[2] = v1.x; f[3] = v1.y;
    f[4] = v2.x; f[5] = v2.y; f[6] = v3.x; f[7] = v3.y;
}
__device__ inline unsigned f32x4_to_fp8(float a, float b, float c, float d) {
    unsigned r = __builtin_amdgcn_cvt_pk_fp8_f32(a, b, 0, false);
    r = __builtin_amdgcn_cvt_pk_fp8_f32(c, d, r, true);
    return r;
}

// ---- chunked histograms -> ushort partials: block = (chunk, type, half) ----
__global__ __launch_bounds__(1024) void hist_kernel(const int* __restrict__ src,
                                                    const int* __restrict__ dst,
                                                    unsigned short* __restrict__ Hs16,
                                                    unsigned short* __restrict__ Hd16) {
    __shared__ unsigned hist[HALF / 2];  // 50 KB
    int bx = blockIdx.x;                 // 256 blocks
    int c = bx >> 2, t = bx & 1, h = (bx >> 1) & 1;
    const int* ids = t ? dst : src;
    unsigned short* H = t ? Hd16 : Hs16;
    int base = h * HALF;
    for (int j = threadIdx.x; j < HALF / 2; j += 1024) hist[j] = 0;
    __syncthreads();
    int e0 = c * EPC;
    for (int e = e0 + threadIdx.x; e < e0 + EPC; e += 1024) {
        int id = ids[e] - base;
        if ((unsigned)id < (unsigned)HALF)
            atomicAdd(&hist[id >> 1], 1u << ((id & 1) * 16));
    }
    __syncthreads();
    for (int j = threadIdx.x; j < HALF / 2; j += 1024)
        *(unsigned*)&H[(size_t)c * N_NODES + base + 2 * j] = hist[j];
}

// ---- reduceN: 196 blocks x 256 thr, one node/thread -> norms/degd/bsums ----
__global__ __launch_bounds__(256) void reduceN_kernel(const unsigned short* __restrict__ Hs16,
                                                      const unsigned short* __restrict__ Hd16,
                                                      float* __restrict__ onorm,
                                                      float* __restrict__ inorm,
                                                      int* __restrict__ degd,
                                                      int* __restrict__ bsums) {
    __shared__ int wsum[4];
    int i = blockIdx.x * 256 + threadIdx.x;
    int dd = 0;
    if (i < N_NODES) {
        int ds = 0;
        for (int c = 0; c < CH; c++) {
            ds += Hs16[(size_t)c * N_NODES + i];
            dd += Hd16[(size_t)c * N_NODES + i];
        }
        onorm[i] = rsqrtf(fmaxf((float)ds, 1.0f));
        inorm[i] = rsqrtf(fmaxf((float)dd, 1.0f));
        degd[i] = dd;
    }
    int v = dd;
#pragma unroll
    for (int off = 32; off; off >>= 1) v += __shfl_down(v, off);
    if ((threadIdx.x & 63) == 0) wsum[threadIdx.x >> 6] = v;
    __syncthreads();
    if (threadIdx.x == 0)
        bsums[blockIdx.x] = wsum[0] + wsum[1] + wsum[2] + wsum[3];
}

// ---- tq: t[s] partials via LDS float bins + fused prep tail ----
// main: block (c,q) accumulates inorm[dst] into src bins of its quarter.
// tail: grid-stride cvt (feat*onorm -> fp8 xq) + wprep (W -> n-major bf16).
// tail outputs consumed only by later dispatches -> no sync needed.
__global__ __launch_bounds__(1024) void tq_kernel(const int* __restrict__ src,
                                                  const int* __restrict__ dst,
                                                  const float* __restrict__ inorm,
                                                  float* __restrict__ Tq,
                                                  const float* __restrict__ feat,
                                                  const float* __restrict__ onorm,
                                                  uint2* __restrict__ xq,
                                                  const float* __restrict__ W1,
                                                  const float* __restrict__ W2,
                                                  unsigned short* __restrict__ Wt) {
    __shared__ float a[QTR];  // 50 KB
    int bx = blockIdx.x;      // 256 blocks
    int c = bx >> 2, q = bx & 3;
    int base = q * QTR;
    for (int j = threadIdx.x; j < QTR; j += 1024) a[j] = 0.0f;
    __syncthreads();
    int e0 = c * EPC;
    for (int e = e0 + threadIdx.x; e < e0 + EPC; e += 1024) {
        int s = src[e] - base;
        if ((unsigned)s < (unsigned)QTR)
            atomicAdd(&a[s], inorm[dst[e]]);   // LDS float atomic (ds_add_f32)
    }
    __syncthreads();
    for (int j = threadIdx.x; j < QTR; j += 1024)
        Tq[(size_t)c * N_NODES + base + j] = a[j];

    // fused prep tail (grid-stride over the full machine)
    int T = gridDim.x * 1024;
    int id0 = bx * 1024 + threadIdx.x;
    for (int i = id0; i < N_NODES * F / 8; i += T) {
        float w = onorm[i >> 4];   // 16 uint2 per 128-col row
        const float4* xv = (const float4*)feat;
        float4 v0 = xv[i * 2], v1 = xv[i * 2 + 1];
        uint2 o;
        o.x = f32x4_to_fp8(v0.x * w, v0.y * w, v0.z * w, v0.w * w);
        o.y = f32x4_to_fp8(v1.x * w, v1.y * w, v1.z * w, v1.w * w);
        xq[i] = o;
    }
    for (int i = id0; i < 2 * F * F; i += T) {
        int wi = i >> 14, rem = i & 16383;
        int n = rem >> 7, k = rem & 127;
        const float* W = wi ? W2 : W1;
        Wt[(size_t)wi * F * F + (size_t)n * F + k] = f2bf(W[k * F + n]);
    }
}

// ---- scanC: rowst + inline scan of bsums (4 per scanC block) + colpref + qt ----
__global__ __launch_bounds__(1024) void scanC_kernel(const int* __restrict__ deg,
                                                     const int* __restrict__ bsums,
                                                     int* __restrict__ rowst,
                                                     const unsigned short* __restrict__ Hd16,
                                                     int* __restrict__ P,
                                                     const float* __restrict__ Tq,
                                                     float* __restrict__ qt) {
    __shared__ int wsum[16];
    int t = threadIdx.x, lane = t & 63, w = t >> 6;
    int i = blockIdx.x * 1024 + t;
    int v = (i < N_NODES) ? deg[i] : 0;
    int incl = v;
#pragma unroll
    for (int off = 1; off < 64; off <<= 1) {
        int u = __shfl_up(incl, off);
        if (lane >= off) incl += u;
    }
    if (lane == 63) wsum[w] = incl;
    __syncthreads();
    if (t == 0) {
        int s = 0;                      // inline scanB: 4 reduceN blocks per scanC block
        int kmax = min(4 * (int)blockIdx.x, RN_NB);
        for (int k = 0; k < kmax; k++) s += bsums[k];
#pragma unroll
        for (int k = 0; k < 16; k++) { int x = wsum[k]; wsum[k] = s; s += x; }
    }
    __syncthreads();
    incl += wsum[w];
    if (i < N_NODES) {
        int s = incl - v;          // exclusive prefix
        rowst[i] = s;
        if (i == N_NODES - 1) rowst[N_NODES] = incl;
        float tsum = 0.0f;
        for (int c = 0; c < CH; c++) {
            size_t o = (size_t)c * N_NODES + i;
            P[o] = s; s += Hd16[o];
            tsum += Tq[o];
        }
        qt[i] = tsum;              // xq is onorm-prescaled, so q == t
    }
}

// ---- atomic-free scatter: block = (chunk, quarter); writes bare src int ----
__global__ __launch_bounds__(1024) void scatter2_kernel(const int* __restrict__ src,
                                                        const int* __restrict__ dst,
                                                        const int* __restrict__ P,
                                                        int* __restrict__ esrc) {
    __shared__ int cur[QTR];  // 50 KB
    int bx = blockIdx.x;      // 256 blocks
    int c = bx >> 2, q = bx & 3;
    int base = q * QTR;
    for (int j = threadIdx.x; j < QTR; j += 1024)
        cur[j] = P[(size_t)c * N_NODES + base + j];
    __syncthreads();
    int e0 = c * EPC;
    for (int e = e0 + threadIdx.x; e < e0 + EPC; e += 1024) {
        int d = dst[e] - base;
        if ((unsigned)d < (unsigned)QTR) {
            int pos = atomicAdd(&cur[d], 1);   // LDS atomic only
            esrc[pos] = src[e];
        }
    }
}

// ---- aggregation: 4 waves/block, 1 dst row/wave; 16 lanes/edge fp8 uint2 ----
__global__ __launch_bounds__(256) void agg_csr_kernel(const uint2* __restrict__ xq,
                                                      uint4* __restrict__ mb,
                                                      const int* __restrict__ rowst,
                                                      const int* __restrict__ esrc,
                                                      const float* __restrict__ inorm) {
    int w = threadIdx.x >> 6;
    int lane = threadIdx.x & 63;
    int g = lane >> 4, t = lane & 15;
    int row = blockIdx.x * 4 + w;
    int beg = __builtin_amdgcn_readfirstlane(rowst[row]);
    int end = __builtin_amdgcn_readfirstlane(rowst[row + 1]);
    float acc[8];
#pragma unroll
    for (int k = 0; k < 8; k++) acc[k] = 0.0f;

    for (int e = beg; e < end; e += 16) {   // clamped, 4 gathers in flight
        int ea = min(e + g,      end - 1);
        int eb = min(e + 4 + g,  end - 1);
        int ec = min(e + 8 + g,  end - 1);
        int ed = min(e + 12 + g, end - 1);
        int sa = esrc[ea], sb = esrc[eb], sc = esrc[ec], sd = esrc[ed];
        uint2 ua = xq[(size_t)sa * 16 + t];
        uint2 ub = xq[(size_t)sb * 16 + t];
        uint2 uc = xq[(size_t)sc * 16 + t];
        uint2 ud = xq[(size_t)sd * 16 + t];
        float wa = (e + g      < end) ? 1.0f : 0.0f;
        float wb = (e + 4 + g  < end) ? 1.0f : 0.0f;
        float wc = (e + 8 + g  < end) ? 1.0f : 0.0f;
        float wd = (e + 12 + g < end) ? 1.0f : 0.0f;
        float fa[8], fb[8], fc[8], fd[8];
        fp8x8_to_f32(ua, fa); fp8x8_to_f32(ub, fb);
        fp8x8_to_f32(uc, fc); fp8x8_to_f32(ud, fd);
#pragma unroll
        for (int k = 0; k < 8; k++)
            acc[k] += fa[k] * wa + fb[k] * wb + fc[k] * wc + fd[k] * wd;
    }
#pragma unroll
    for (int k = 0; k < 8; k++) {
        acc[k] += __shfl_xor(acc[k], 16, 64);
        acc[k] += __shfl_xor(acc[k], 32, 64);
    }
    if (g == 0) {
        float inw = inorm[row];
        uint4 o;
        o.x = packbf2(acc[0] * inw, acc[1] * inw);
        o.y = packbf2(acc[2] * inw, acc[3] * inw);
        o.z = packbf2(acc[4] * inw, acc[5] * inw);
        o.w = packbf2(acc[6] * inw, acc[7] * inw);
        mb[(size_t)row * 16 + t] = o;
    }
}

// ---- MFMA GEMM, single bf16 W staged in LDS (one phase, 64 MFMA) ----
// FINAL=0: Y8 = fp8(onorm[row] * relu(A@W+b))  (layer 1)
// FINAL=1: no Y8; part2[block][col] = sum_rows qt[row]*onorm[row]*relu(...)
template <int FINAL>
__global__ __launch_bounds__(256) void mfma_gemm_kernel(const unsigned short* __restrict__ A,
                                                        const unsigned short* __restrict__ Wt,
                                                        const float* __restrict__ bias,
                                                        const float* __restrict__ onorm,
                                                        unsigned char* __restrict__ Y8,
                                                        const float* __restrict__ qt,
                                                        float* __restrict__ part2) {
    __shared__ uint4 sB[F * BSTRIDE];   // 34816 B
    __shared__ float sPf[4][F];         // 2 KB (FINAL only)
    int tid = threadIdx.x;
    int w = tid >> 6;
    int lane = tid & 63;
    int quad = lane >> 4, r16 = lane & 15;
    int row0 = blockIdx.x * 64 + w * 16;

    // preload A-frags (global) so loads overlap staging
    const uint4* Arow = (const uint4*)(A + (size_t)(row0 + r16) * F);
    uint4 a[4];
#pragma unroll
    for (int kk = 0; kk < 4; kk++) a[kk] = Arow[kk * 4 + quad];

    const uint4* G = (const uint4*)Wt;
    for (int j = tid; j < F * 16; j += 256)
        sB[(j >> 4) * BSTRIDE + (j & 15)] = G[j];

    f32x4 acc[8];
#pragma unroll
    for (int t = 0; t < 8; t++) acc[t] = (f32x4){0.f, 0.f, 0.f, 0.f};
    __syncthreads();

#pragma unroll
    for (int kk = 0; kk < 4; kk++) {
        bf16x8 av = __builtin_bit_cast(bf16x8, a[kk]);
#pragma unroll
        for (int t = 0; t < 8; t++) {
            bf16x8 bv = __builtin_bit_cast(bf16x8,
                sB[(t * 16 + r16) * BSTRIDE + kk * 4 + quad]);
            acc[t] = __builtin_amdgcn_mfma_f32_16x16x32_bf16(av, bv, acc[t], 0, 0, 0);
        }
    }

    float rw[4];
#pragma unroll
    for (int reg = 0; reg < 4; reg++) {
        int row = row0 + quad * 4 + reg;
        rw[reg] = (row < N_NODES) ? (FINAL ? qt[row] * onorm[row] : onorm[row]) : 0.0f;
    }

    if (!FINAL) {
#pragma unroll
        for (int t = 0; t < 8; t++) {
            int col = t * 16 + r16;
            float bb = bias[col];
#pragma unroll
            for (int reg = 0; reg < 4; reg++) {
                int row = row0 + quad * 4 + reg;
                if (row < N_NODES) {
                    float v = fmaxf(acc[t][reg] + bb, 0.0f) * rw[reg];
                    unsigned p = __builtin_amdgcn_cvt_pk_fp8_f32(v, v, 0, false);
                    Y8[(size_t)row * F + col] = (unsigned char)(p & 0xFF);
                }
            }
        }
    } else {
#pragma unroll
        for (int t = 0; t < 8; t++) {
            int col = t * 16 + r16;
            float bb = bias[col];
            float p = 0.0f;
#pragma unroll
            for (int reg = 0; reg < 4; reg++)
                p += fmaxf(acc[t][reg] + bb, 0.0f) * rw[reg];
            p += __shfl_xor(p, 16, 64);      // reduce over quad
            p += __shfl_xor(p, 32, 64);
            if (quad == 0) sPf[w][col] = p;
        }
        __syncthreads();
        if (tid < F)
            part2[(size_t)blockIdx.x * F + tid] =
                sPf[0][tid] + sPf[1][tid] + sPf[2][tid] + sPf[3][tid];
    }
}

// ---- final: c = (1/N) * sum_b part2[b] (b < GB), out = c @ W3 + b3 ----
__global__ __launch_bounds__(1024) void final_kernel(const float* __restrict__ part2,
                                                     const float* __restrict__ W3,
                                                     const float* __restrict__ b3,
                                                     float* __restrict__ out) {
    __shared__ float sc[8][F];  // 4 KB
    int tid = threadIdx.x;
    int col = tid & 127, sl = tid >> 7;
    float acc = 0.0f;
    for (int b = sl; b < GB; b += 8) acc += part2[(size_t)b * F + col];
    sc[sl][col] = acc;
    __syncthreads();
    if (tid < F) {
        float s = 0.0f;
#pragma unroll
        for (int k = 0; k < 8; k++) s += sc[k][tid];
        sc[0][tid] = s * (1.0f / (float)N_NODES);
    }
    __syncthreads();
    if (tid < F) {
        float o = b3[tid];
        for (int k = 0; k < F; k++) o += sc[0][k] * W3[k * F + tid];
        out[tid] = o;
    }
}

extern "C" void kernel_launch(void* const* d_in, const int* in_sizes, int n_in,
                              void* d_out, int out_size, void* d_ws, size_t ws_size,
                              hipStream_t stream) {
    const float* feat = (const float*)d_in[0];
    const float* W1   = (const float*)d_in[1];
    const float* b1   = (const float*)d_in[2];
    const float* W2   = (const float*)d_in[3];
    const float* b2   = (const float*)d_in[4];
    const float* W3   = (const float*)d_in[5];
    const float* b3   = (const float*)d_in[6];
    const int*   src  = (const int*)d_in[7];
    const int*   dst  = (const int*)d_in[8];
    float* out = (float*)d_out;

    // workspace layout (~70 MB, 16B-aligned blocks first)
    char* ws = (char*)d_ws;
    size_t off = 0;
    uint4* mb    = (uint4*)(ws + off); off += (size_t)N_NODES * F * 2;       // 12.8 MB bf16
    float* Tq    = (float*)(ws + off); off += (size_t)CH * N_NODES * 4;      // 12.8 MB
    int*   P     = (int*)  (ws + off); off += (size_t)CH * N_NODES * 4;      // 12.8 MB
    unsigned short* Hs16 = (unsigned short*)(ws + off); off += (size_t)CH * N_NODES * 2;  // 6.4 MB
    unsigned short* Hd16 = (unsigned short*)(ws + off); off += (size_t)CH * N_NODES * 2;  // 6.4 MB
    uint2* xq    = (uint2*)(ws + off); off += (size_t)N_NODES * F;           // 6.4 MB fp8
    uint2* hq    = (uint2*)(ws + off); off += (size_t)N_NODES * F;           // 6.4 MB fp8
    unsigned short* Wt = (unsigned short*)(ws + off); off += 2 * F * F * 2;  // 64 KB bf16
    float* part2 = (float*)(ws + off); off += (size_t)GB * F * 4;            // 400 KB
    int*   esrc  = (int*)  (ws + off); off += (size_t)N_EDGES * 4;           // 3.2 MB
    float* onorm = (float*)(ws + off); off += N_NODES * 4;
    float* inorm = (float*)(ws + off); off += N_NODES * 4;
    float* qt    = (float*)(ws + off); off += N_NODES * 4;
    int*   degd  = (int*)  (ws + off); off += N_NODES * 4;
    int*   rowst = (int*)  (ws + off); off += (N_NODES + 1) * 4;
    int*   bsums = (int*)  (ws + off); off += 256 * 4;

    // CSR build + t[s] + fused prep — zero global atomics, zero memsets
    hist_kernel<<<4 * CH, 1024, 0, stream>>>(src, dst, Hs16, Hd16);
    reduceN_kernel<<<RN_NB, 256, 0, stream>>>(Hs16, Hd16, onorm, inorm, degd, bsums);
    tq_kernel<<<4 * CH, 1024, 0, stream>>>(src, dst, inorm, Tq,
                                           feat, onorm, xq, W1, W2, Wt);
    scanC_kernel<<<SCAN_NB, 1024, 0, stream>>>(degd, bsums, rowst, Hd16, P, Tq, qt);
    scatter2_kernel<<<4 * CH, 1024, 0, stream>>>(src, dst, P, esrc);

    // layer 1: agg(xq) -> mb (bf16), gemm -> hq (fp8, onorm-prescaled)
    agg_csr_kernel<<<AGG_NB, 256, 0, stream>>>(xq, mb, rowst, esrc, inorm);
    mfma_gemm_kernel<0><<<GB, 256, 0, stream>>>((const unsigned short*)mb, Wt, b1,
                                                onorm, (unsigned char*)hq, qt, part2);
    // layer 2: agg(hq) -> mb, gemm(+fused layer-3 column sum) -> part2
    agg_csr_kernel<<<AGG_NB, 256, 0, stream>>>(hq, mb, rowst, esrc, inorm);
    mfma_gemm_kernel<1><<<GB, 256, 0, stream>>>((const unsigned short*)mb, Wt + F * F,
                                                b2, onorm, (unsigned char*)hq, qt, part2);
    // final: c = (1/N) sum_b part2[b]; out = c @ W3 + b3
    final_kernel<<<1, 1024, 0, stream>>>(part2, W3, b3, out);
}